// Round 2
// baseline (318.566 us; speedup 1.0000x reference)
//
#include <hip/hip_runtime.h>

typedef __bf16 bf16x8 __attribute__((ext_vector_type(8)));
typedef __bf16 bf16x4 __attribute__((ext_vector_type(4)));
typedef float f32x4 __attribute__((ext_vector_type(4)));
typedef unsigned long long u64;

#define NCH 8            // row-chunks per recurrence
#define CELLS 16         // rows per chunk
#define NG 256           // 4 gates * 64 units
#define L2E 1.44269504089f
#define RDEPTH 8                        // ring depth (tag mod 8)
#define NLINK (16 * 7)                  // (g, producer ch 0..6)
#define RING_U64 (NLINK * RDEPTH * 64)  // 448 KiB
#define PROG_OFF (RING_U64 * 8)         // byte offset of progress flags

__device__ __forceinline__ unsigned short f2bfbits(float f) {
  __bf16 b = (__bf16)f;
  return __builtin_bit_cast(unsigned short, b);
}
__device__ __forceinline__ float sigm2(float x) {  // arg pre-scaled by log2e
  return __builtin_amdgcn_rcpf(1.f + __builtin_amdgcn_exp2f(-x));
}
__device__ __forceinline__ float tanh2(float x) {  // arg pre-scaled by 2*log2e
  return 1.f - 2.f * __builtin_amdgcn_rcpf(1.f + __builtin_amdgcn_exp2f(x));
}
// LDS-only barrier: vmcnt stays in flight (out stores, x prefetch, ring ops)
__device__ __forceinline__ void barrier_lds() {
  asm volatile("s_waitcnt lgkmcnt(0)" ::: "memory");
  __builtin_amdgcn_s_barrier();
}
// 16B-granule XOR swizzles. h rows are 128B bf16; buffer row r holds chunk
// row r-1 (row 0 = upstream guard; row0 swizzle is identity -> linear copy).
__device__ __forceinline__ int hix(int row, int byteoff) {
  return row * 128 + (byteoff ^ ((row & 7) << 4));
}
__device__ __forceinline__ int cix(int row, int q) {  // 64-f32 rows
  return row * 64 + ((((q >> 2) ^ (row & 7)) << 2) | (q & 3));
}

// ROW-partitioned 2D-LSTM pipeline; WAVE-SPECIALIZED single-barrier step.
// Block = (chunk ch, recurrence g), 512 thr = 8 waves (2/SIMD):
//   waves 0-3 (compute): post-barrier critical region = {h(d-1) b128 reads,
//     1 c read, 4 zbuf b128 reads (accA from helpers), h-sum with inv
//     FOLDED into the A-fragment, 16 h@Wr MFMA CHAINED FROM C=accA (z pops
//     out of MFMA: no z adds, no acc inits), LSTM epilogue, publish,
//     state/out writes}. h_ul carried in f32 registers; c_up/c_left/c_ul
//     carried lane-locally (only pu[0] crosses lanes via LDS).
//   waves 4-7 (helper): compute accA(d+1)=x@Wk+b (8 MFMA) -> zbuf dbuf;
//     stage x(d+2)->xt dbuf, prefetch x(d+3); wave 4 copies ring guard tag
//     d into row 0 of write buffers and polls tags d+1,d+2 every 2 steps.
__global__ __launch_bounds__(512, 1) void mdrnn_kernel(
    const float* __restrict__ x, const float* __restrict__ Wk,
    const float* __restrict__ Wr, const float* __restrict__ bias,
    float* __restrict__ out, char* __restrict__ ws) {
  __shared__ __align__(16) unsigned char xt[2][CELLS * 128];   // 4 KiB
  __shared__ __align__(16) unsigned char hbuf[2][17 * 128];    // 4.25 KiB
  __shared__ __align__(16) float cbuf[2][13 * 64];             // 6.5 KiB
  __shared__ __align__(16) unsigned char gbh[8 * 128];         // 1 KiB
  __shared__ __align__(16) float gbc[8 * 64];                  // 2 KiB
  __shared__ __align__(16) float zbuf[2][4096];                // 32 KiB accA

  u64* __restrict__ ring = (u64*)ws;
  int* __restrict__ prog = (int*)(ws + PROG_OFF);  // 16-int (64B) stride

  const int tid = threadIdx.x;
  const bool isComp = (tid < 256);
  const int L = tid & 63;
  const int lo16 = L & 15;
  const int hi16 = L >> 4;
  const int wq = (tid >> 6) & 3;     // wave id within compute/helper group
  const int u = wq * 16 + lo16;      // unit-group index (both roles)
  const int hm0 = (tid >> 4) & 15;   // helper: staged row
  const int hq16 = tid & 15;         // helper: channel quad

  const int ch = blockIdx.x >> 4;   // bx%8 == g%8 -> chain on one XCD
  const int g = blockIdx.x & 15;
  const int f = g >> 2;
  const int bb = g & 3;
  const int fh = (f >> 1) & 1;
  const int fw = f & 1;
  const int R0 = ch * CELLS;
  const int D1 = R0 + 142;
  const int linkDn = g * 7 + ch - 1;
  const int linkUp = g * 7 + ch;

  for (int i = tid; i < 2 * CELLS * 32; i += 512) ((int*)xt)[i] = 0;
  for (int i = tid; i < 2 * 17 * 32; i += 512) ((int*)hbuf)[i] = 0;
  for (int i = tid; i < 2 * 13 * 64; i += 512) ((float*)cbuf)[i] = 0.f;
  for (int i = tid; i < 8 * 32; i += 512) ((int*)gbh)[i] = 0;
  for (int i = tid; i < 8 * 64; i += 512) gbc[i] = 0.f;

  // ---- per-role constants ----
  float bsc[4] = {0.f, 0.f, 0.f, 0.f};
  bf16x8 wkh[4][2], wrh[4][2], wrl[4][2];
  int oidx[4];
  int oStep = 0, cbase = 0;
  int o_hu0 = 0, o_hu1 = 0, o_hl0 = 0, o_hl1 = 0, o_cu0 = 0, o_c4 = 0;
  int o_hw[4] = {0, 0, 0, 0};
  float invBase = 1.f / 3.f;
  if (isComp) {
    const float* Wrf = Wr + f * (64 * NG);
#pragma unroll
    for (int t = 0; t < 4; ++t) {
      const float st = (t == 2) ? (2.f * L2E) : L2E;
#pragma unroll
      for (int kt = 0; kt < 2; ++kt)
#pragma unroll
        for (int jj = 0; jj < 8; ++jj) {
          int k = kt * 32 + hi16 * 8 + jj;
          float vr = Wrf[k * NG + t * 64 + u] * st;
          __bf16 vh = (__bf16)vr;
          wrh[t][kt][jj] = vh;
          wrl[t][kt][jj] = (__bf16)(vr - (float)vh);
        }
    }
    const int ccStep = fw ? -1 : 1;
#pragma unroll
    for (int j = 0; j < 4; ++j) {
      int ro = R0 + hi16 * 4 + j;
      int rr = fh ? 127 - ro : ro;
      int c0 = R0 - ro;
      oidx[j] = ((bb * 128 + rr) * 128 + (fw ? 127 - c0 : c0)) * NG + f * 64 + u;
      int lm = hi16 * 4 + j;
      o_hw[j] = hix(lm + 1, u * 2);
    }
    oStep = ccStep * NG;
    cbase = -hi16 * 4;
    o_hu0 = hix(lo16, hi16 * 16);       // h_up  (buffer row lo16)
    o_hu1 = hix(lo16, 64 + hi16 * 16);
    o_hl0 = hix(lo16 + 1, hi16 * 16);   // h_left (buffer row lo16+1)
    o_hl1 = hix(lo16 + 1, 64 + hi16 * 16);
    o_cu0 = cix(hi16 * 4, u);           // only cross-lane c read
    o_c4 = cix(hi16 * 4 + 4, u);        // only live c write (j==3, hi16<3)
    invBase = (R0 == 0 && lo16 == 0) ? 1.f : (1.f / 3.f);
  } else {
    const float* Wkf = Wk + f * (64 * NG);
#pragma unroll
    for (int t = 0; t < 4; ++t) {
      const float st = (t == 2) ? (2.f * L2E) : L2E;
      bsc[t] = bias[f * NG + t * 64 + u] * st;
#pragma unroll
      for (int kt = 0; kt < 2; ++kt)
#pragma unroll
        for (int jj = 0; jj < 8; ++jj) {
          int k = kt * 32 + hi16 * 8 + jj;
          wkh[t][kt][jj] = (__bf16)(Wkf[k * NG + t * 64 + u] * st);
        }
    }
  }
  const int o_ax0 = hix(lo16, hi16 * 16);
  const int o_ax1 = hix(lo16, 64 + hi16 * 16);

  // ---- helper-wave x addressing ----
  const int ccStepH = fw ? -1 : 1;
  const int rx = R0 + hm0;
  const int rrx = fh ? 127 - rx : rx;
  int cx = R0 - rx;
  int xidx = ((bb * 128 + rrx) * 128 + (fw ? 127 - cx : cx)) * 64 + hq16 * 4;
  const int xStep = ccStepH * 64;
  float4 px;
  bool pxv = false;
  auto ldg = [&]() {
    pxv = ((unsigned)cx <= 127u);
    px = make_float4(0.f, 0.f, 0.f, 0.f);
    if (pxv) px = *(const float4*)(x + xidx);
    xidx += xStep;
    ++cx;
  };
  auto stx = [&](unsigned char* buf) {
    if (pxv) {
      bf16x4 pk;
      pk[0] = (__bf16)px.x; pk[1] = (__bf16)px.y;
      pk[2] = (__bf16)px.z; pk[3] = (__bf16)px.w;
      *(bf16x4*)(buf + hix(hm0, hq16 * 8)) = pk;
    }
  };
  // helper: accA(tile) = x@Wk + b -> zbuf[bi] (conflict-free b128 lanes)
  auto accx = [&](const unsigned char* xp, int bi) {
    bf16x8 a0 = *(const bf16x8*)(xp + o_ax0);
    bf16x8 a1 = *(const bf16x8*)(xp + o_ax1);
    float* zw = &zbuf[bi][0] + (wq * 64 + L) * 4;
#pragma unroll
    for (int t = 0; t < 4; ++t) {
      f32x4 az = (f32x4){bsc[t], bsc[t], bsc[t], bsc[t]};
      az = __builtin_amdgcn_mfma_f32_16x16x32_bf16(a0, wkh[t][0], az, 0, 0, 0);
      az = __builtin_amdgcn_mfma_f32_16x16x32_bf16(a1, wkh[t][1], az, 0, 0, 0);
      *(f32x4*)(zw + t * 1024) = az;
    }
  };

  __syncthreads();  // zero-init visible

  if (!isComp) {
    ldg();                  // px = x(R0)
    stx(&xt[R0 & 1][0]);
    ldg();                  // px = x(R0+1)
  }
  __syncthreads();  // x(R0) visible for accx fragment reads

  if (!isComp) {
    accx(&xt[R0 & 1][0], R0 & 1);  // zbuf[R0&1] = accA(R0)
    stx(&xt[(R0 + 1) & 1][0]);     // stage x(R0+1)
    ldg();                         // px = x(R0+2)
    // pre-loop poll (helper wave 0): tags R0-1 and R0; fold R0-1 into row 0
    if (wq == 0 && ch > 0) {
#pragma unroll
      for (int k = 0; k < 2; ++k) {
        const int q = R0 - 1 + k;
        u64* src = ring + ((linkDn * RDEPTH + (q & 7)) << 6) + L;
        u64 v;
        int spin = 0;
        for (;;) {
          v = __hip_atomic_load(src, __ATOMIC_RELAXED, __HIP_MEMORY_SCOPE_AGENT);
          if ((unsigned short)(v >> 48) == (unsigned short)q ||
              spin >= (1 << 22))
            break;
          ++spin;
          __builtin_amdgcn_s_sleep(2);
        }
        *(unsigned short*)(gbh + (q & 7) * 128 + L * 2) =
            (unsigned short)(v >> 32);
        gbc[(q & 7) * 64 + L] = __uint_as_float((unsigned)v);
        if (k == 0) {  // guard tag R0-1 -> row 0 of the "previous" buffers
          *(unsigned short*)(&hbuf[(R0 + 1) & 1][0] + L * 2) =
              (unsigned short)(v >> 32);
          cbuf[(R0 + 1) & 1][L] = __uint_as_float((unsigned)v);
        }
      }
      if (L == 0)
        __hip_atomic_store(&prog[linkDn * 16], R0, __ATOMIC_RELAXED,
                           __HIP_MEMORY_SCOPE_AGENT);
    }
  }
  __syncthreads();

  // ---- rotating state (all threads; uniform) ----
  unsigned char* hW = &hbuf[R0 & 1][0];
  unsigned char* hP = &hbuf[(R0 + 1) & 1][0];
  float* cW = &cbuf[R0 & 1][0];
  float* cP = &cbuf[(R0 + 1) & 1][0];
  int gOff = (R0 & 7) * 128;

  // ---- compute-wave carried state ----
  float hxf0[8], hxf1[8];  // carried h_ul = prev step's h_up, kept in f32
  float cnv[4];            // carried c(d-1)[row lm] (this lane's last cn)
  float puv[4];            // carried c_ul = prev step's c_up
  int gateSeen = 0;
  if (isComp) {
#pragma unroll
    for (int e = 0; e < 8; ++e) { hxf0[e] = 0.f; hxf1[e] = 0.f; }
#pragma unroll
    for (int j = 0; j < 4; ++j) { cnv[j] = 0.f; puv[j] = 0.f; }
    __builtin_amdgcn_s_setprio(1);  // compute waves favored over helpers
  }

  for (int d = R0; d <= D1; ++d) {
    if (isComp) {
      // ---- post-barrier critical region ----
      bf16x8 hu0 = *(const bf16x8*)(hP + o_hu0);
      bf16x8 hu1 = *(const bf16x8*)(hP + o_hu1);
      bf16x8 hl0 = *(const bf16x8*)(hP + o_hl0);
      bf16x8 hl1 = *(const bf16x8*)(hP + o_hl1);
      const float pu0 = cP[o_cu0];
      const float* zb = &zbuf[d & 1][0] + (wq * 64 + L) * 4;
      f32x4 zacc[4];
#pragma unroll
      for (int t = 0; t < 4; ++t) zacc[t] = *(const f32x4*)(zb + t * 1024);

      const bool pub = (ch < NCH - 1) && (d >= R0 + 15);
      if (pub && d >= R0 + 23 && gateSeen < d - 8)  // early gate refresh
        gateSeen = __hip_atomic_load(&prog[linkUp * 16], __ATOMIC_RELAXED,
                                     __HIP_MEMORY_SCOPE_AGENT);

      // h-sum A-fragments; neighbor-count 1/cnt folded into A row scale
      const float inv_a = ((d - R0) == lo16) ? 1.f : invBase;
      bf16x8 ah0, ah1;
#pragma unroll
      for (int e = 0; e < 8; ++e) {
        const float a0 = (float)hu0[e], a1 = (float)hu1[e];
        ah0[e] = (__bf16)(inv_a * (a0 + (float)hl0[e] + hxf0[e]));
        ah1[e] = (__bf16)(inv_a * (a1 + (float)hl1[e] + hxf1[e]));
        hxf0[e] = a0; hxf1[e] = a1;
      }
      float csj[4];
#pragma unroll
      for (int j = 0; j < 4; ++j) {
        const float puj = (j == 0) ? pu0 : cnv[j - 1];
        csj[j] = puj + cnv[j] + puv[j];
        puv[j] = puj;
      }

      // ---- 16 MFMA chained from C=accA: z = accA + (inv*hsum)@Wr(hi+lo)
#pragma unroll
      for (int t = 0; t < 4; ++t)
        zacc[t] = __builtin_amdgcn_mfma_f32_16x16x32_bf16(ah0, wrh[t][0], zacc[t], 0, 0, 0);
#pragma unroll
      for (int t = 0; t < 4; ++t)
        zacc[t] = __builtin_amdgcn_mfma_f32_16x16x32_bf16(ah1, wrh[t][1], zacc[t], 0, 0, 0);
#pragma unroll
      for (int t = 0; t < 4; ++t)
        zacc[t] = __builtin_amdgcn_mfma_f32_16x16x32_bf16(ah0, wrl[t][0], zacc[t], 0, 0, 0);
#pragma unroll
      for (int t = 0; t < 4; ++t)
        zacc[t] = __builtin_amdgcn_mfma_f32_16x16x32_bf16(ah1, wrl[t][1], zacc[t], 0, 0, 0);

      // ---- epilogue: LSTM, publish (top row first), state/out writes ----
#pragma unroll
      for (int jj = 0; jj < 4; ++jj) {
        const int j = 3 - jj;
        const int lm = hi16 * 4 + j;
        const int r = R0 + lm;
        const int cj = cbase - j;
        const bool ok = ((unsigned)cj <= 127u);
        const float inv = (cj == 0 || r == 0) ? 1.f : (1.f / 3.f);
        const float cpj = csj[j] * inv;
        float cn = sigm2(zacc[1][j]) * cpj + sigm2(zacc[0][j]) * tanh2(zacc[2][j]);
        float hn = sigm2(zacc[3][j]) * tanh2(2.f * L2E * cn);
        if (pub && lm == CELLS - 1) {
          if (d >= R0 + 23 && gateSeen < d - 8) {  // ring-wrap gate (backstop)
            int spin = 0;
            do {
              gateSeen = __hip_atomic_load(&prog[linkUp * 16], __ATOMIC_RELAXED,
                                           __HIP_MEMORY_SCOPE_AGENT);
            } while (gateSeen < d - 8 && ++spin < (1 << 22));
          }
          u64 v = ((u64)(unsigned short)d << 48) | ((u64)f2bfbits(hn) << 32) |
                  (u64)__float_as_uint(cn);
          u64* dst = ring + ((linkUp * RDEPTH + (d & 7)) << 6) + u;
          __hip_atomic_store(dst, v, __ATOMIC_RELAXED,
                             __HIP_MEMORY_SCOPE_AGENT);
        }
        cn = ok ? cn : 0.f;
        cnv[j] = cn;
        if (j == 3 && hi16 < 3) cW[o_c4] = cn;  // only row others read
        *(unsigned short*)(hW + o_hw[j]) =
            ok ? f2bfbits(hn) : (unsigned short)0;
        if (ok) out[oidx[j]] = hn;
      }
#pragma unroll
      for (int j = 0; j < 4; ++j) oidx[j] += oStep;
      ++cbase;
    } else {
      // ---- helpers: accA(d+1)->zbuf, guard-copy, stage x(d+2), poll ----
      accx(&xt[(d + 1) & 1][0], (d + 1) & 1);
      if (wq == 0 && ch > 0) {  // ring guard tag d -> row 0 of write buffers
        *(unsigned short*)(hW + L * 2) =
            *(const unsigned short*)(gbh + gOff + L * 2);
        cW[L] = gbc[(gOff >> 1) + L];
      }
      stx(&xt[d & 1][0]);  // x(d+2)
      ldg();               // px = x(d+3)

      if (((d - R0) & 1) == 0 && ch > 0 && wq == 0) {
        u64 pv[2];
        const u64* ps[2];
        bool live[2];
#pragma unroll
        for (int k = 0; k < 2; ++k) {
          const int q = d + 1 + k;
          live[k] = (q <= R0 + 126);
          ps[k] = ring + ((linkDn * RDEPTH + (q & 7)) << 6) + L;
          pv[k] = live[k] ? __hip_atomic_load(ps[k], __ATOMIC_RELAXED,
                                              __HIP_MEMORY_SCOPE_AGENT)
                          : 0;
        }
#pragma unroll
        for (int k = 0; k < 2; ++k) {
          const int q = d + 1 + k;
          if (!live[k]) continue;
          int spin = 0;
          while ((unsigned short)(pv[k] >> 48) != (unsigned short)q &&
                 spin < (1 << 22)) {
            ++spin;
            __builtin_amdgcn_s_sleep(1);
            pv[k] = __hip_atomic_load(ps[k], __ATOMIC_RELAXED,
                                      __HIP_MEMORY_SCOPE_AGENT);
          }
          *(unsigned short*)(gbh + (q & 7) * 128 + L * 2) =
              (unsigned short)(pv[k] >> 32);
          gbc[(q & 7) * 64 + L] = __uint_as_float((unsigned)pv[k]);
        }
        if (L == 0)
          __hip_atomic_store(&prog[linkDn * 16], min(d + 2, R0 + 126),
                             __ATOMIC_RELAXED, __HIP_MEMORY_SCOPE_AGENT);
      }
    }

    // rotate buffers (uniform, cheap pointer swaps)
    {
      unsigned char* t1 = hW; hW = hP; hP = t1;
      float* t2 = cW; cW = cP; cP = t2;
      gOff = (gOff + 128) & 1023;
    }
    barrier_lds();  // single barrier: all LDS writes -> next step's reads
  }
}

extern "C" void kernel_launch(void* const* d_in, const int* in_sizes, int n_in,
                              void* d_out, int out_size, void* d_ws, size_t ws_size,
                              hipStream_t stream) {
  const float* x = (const float*)d_in[0];
  const float* Wk = (const float*)d_in[1];
  const float* Wr = (const float*)d_in[2];
  const float* b = (const float*)d_in[3];
  float* out = (float*)d_out;
  // reset ring tags + progress flags every launch (graph-replay determinism)
  hipMemsetAsync(d_ws, 0, PROG_OFF + NLINK * 16 * sizeof(int), stream);
  hipLaunchKernelGGL(mdrnn_kernel, dim3(128), dim3(512), 0, stream, x, Wk, Wr,
                     b, out, (char*)d_ws);
}

// Round 3
// 305.569 us; speedup vs baseline: 1.0425x; 1.0425x over previous
//
#include <hip/hip_runtime.h>

typedef __bf16 bf16x8 __attribute__((ext_vector_type(8)));
typedef __bf16 bf16x4 __attribute__((ext_vector_type(4)));
typedef float f32x4 __attribute__((ext_vector_type(4)));
typedef unsigned long long u64;

#define NCH 8            // row-chunks per recurrence
#define CELLS 16         // rows per chunk
#define NG 256           // 4 gates * 64 units
#define L2E 1.44269504089f
#define RDEPTH 16                       // ring depth (tag mod 16)
#define NLINK (16 * 7)                  // (g, producer ch 0..6)
#define RING_U64 (NLINK * RDEPTH * 64)  // 896 KiB
#define PROG_OFF (RING_U64 * 8)         // byte offset of progress flags

__device__ __forceinline__ unsigned short f2bfbits(float f) {
  __bf16 b = (__bf16)f;
  return __builtin_bit_cast(unsigned short, b);
}
__device__ __forceinline__ float sigm2(float x) {  // arg pre-scaled by log2e
  return __builtin_amdgcn_rcpf(1.f + __builtin_amdgcn_exp2f(-x));
}
__device__ __forceinline__ float tanh2(float x) {  // arg pre-scaled by 2*log2e
  return 1.f - 2.f * __builtin_amdgcn_rcpf(1.f + __builtin_amdgcn_exp2f(x));
}
// LDS-only barrier: vmcnt stays in flight (out stores, x prefetch, ring ops)
__device__ __forceinline__ void barrier_lds() {
  asm volatile("s_waitcnt lgkmcnt(0)" ::: "memory");
  __builtin_amdgcn_s_barrier();
}
// 16B-granule XOR swizzles. h rows are 128B bf16; buffer row r holds chunk
// row r-1 (row 0 = upstream guard; row0 swizzle is identity -> linear copy).
__device__ __forceinline__ int hix(int row, int byteoff) {
  return row * 128 + (byteoff ^ ((row & 7) << 4));
}
__device__ __forceinline__ int cix(int row, int q) {  // 64-f32 rows
  return row * 64 + ((((q >> 2) ^ (row & 7)) << 2) | (q & 3));
}

// ROW-partitioned 2D-LSTM pipeline; WAVE-SPECIALIZED single-barrier step.
// Block = (chunk ch, recurrence g), 512 thr = 8 waves (2/SIMD):
//   waves 0-3 (compute): post-barrier critical region = {h(d-1) b128 reads,
//     1 c read, 4 zbuf b128 reads (accA from helpers), h-sum with inv
//     FOLDED into the A-fragment, 16 h@Wr MFMA chained from C=accA, LSTM
//     epilogue, publish, state/out writes}. h_ul carried in f32 registers;
//     c carried lane-locally (only pu[0] crosses lanes via LDS).
//   waves 4-7 (helper): compute accA(d+1)=x@Wk+b (8 MFMA) -> zbuf dbuf;
//     stage x(d+2)->xt dbuf, prefetch x(d+3). Wave 4: copies ring guard tag
//     d into row 0 of write buffers; every 2 steps polls tags d+2,d+3 with
//     ISSUE-EARLY / RESOLVE-LATE split (accx+guard+stage hides the L2
//     latency). RDEPTH=16 makes the producer ring-wrap gate non-marginal
//     (steady-state skew ~3-6 steps << 16), so gate spins never engage.
__global__ __launch_bounds__(512, 1) void mdrnn_kernel(
    const float* __restrict__ x, const float* __restrict__ Wk,
    const float* __restrict__ Wr, const float* __restrict__ bias,
    float* __restrict__ out, char* __restrict__ ws) {
  __shared__ __align__(16) unsigned char xt[2][CELLS * 128];   // 4 KiB
  __shared__ __align__(16) unsigned char hbuf[2][17 * 128];    // 4.25 KiB
  __shared__ __align__(16) float cbuf[2][13 * 64];             // 6.5 KiB
  __shared__ __align__(16) unsigned char gbh[8 * 128];         // 1 KiB
  __shared__ __align__(16) float gbc[8 * 64];                  // 2 KiB
  __shared__ __align__(16) float zbuf[2][4096];                // 32 KiB accA

  u64* __restrict__ ring = (u64*)ws;
  int* __restrict__ prog = (int*)(ws + PROG_OFF);  // 16-int (64B) stride

  const int tid = threadIdx.x;
  const bool isComp = (tid < 256);
  const int L = tid & 63;
  const int lo16 = L & 15;
  const int hi16 = L >> 4;
  const int wq = (tid >> 6) & 3;     // wave id within compute/helper group
  const int u = wq * 16 + lo16;      // unit-group index (both roles)
  const int hm0 = (tid >> 4) & 15;   // helper: staged row
  const int hq16 = tid & 15;         // helper: channel quad

  const int ch = blockIdx.x >> 4;   // bx%8 == g%8 -> chain on one XCD
  const int g = blockIdx.x & 15;
  const int f = g >> 2;
  const int bb = g & 3;
  const int fh = (f >> 1) & 1;
  const int fw = f & 1;
  const int R0 = ch * CELLS;
  const int D1 = R0 + 142;
  const int linkDn = g * 7 + ch - 1;
  const int linkUp = g * 7 + ch;

  for (int i = tid; i < 2 * CELLS * 32; i += 512) ((int*)xt)[i] = 0;
  for (int i = tid; i < 2 * 17 * 32; i += 512) ((int*)hbuf)[i] = 0;
  for (int i = tid; i < 2 * 13 * 64; i += 512) ((float*)cbuf)[i] = 0.f;
  for (int i = tid; i < 8 * 32; i += 512) ((int*)gbh)[i] = 0;
  for (int i = tid; i < 8 * 64; i += 512) gbc[i] = 0.f;

  // ---- per-role constants ----
  float bsc[4] = {0.f, 0.f, 0.f, 0.f};
  bf16x8 wkh[4][2], wrh[4][2], wrl[4][2];
  int oidx[4];
  int oStep = 0, cbase = 0;
  int o_hu0 = 0, o_hu1 = 0, o_hl0 = 0, o_hl1 = 0, o_cu0 = 0, o_c4 = 0;
  int o_hw[4] = {0, 0, 0, 0};
  float invBase = 1.f / 3.f;
  if (isComp) {
    const float* Wrf = Wr + f * (64 * NG);
#pragma unroll
    for (int t = 0; t < 4; ++t) {
      const float st = (t == 2) ? (2.f * L2E) : L2E;
#pragma unroll
      for (int kt = 0; kt < 2; ++kt)
#pragma unroll
        for (int jj = 0; jj < 8; ++jj) {
          int k = kt * 32 + hi16 * 8 + jj;
          float vr = Wrf[k * NG + t * 64 + u] * st;
          __bf16 vh = (__bf16)vr;
          wrh[t][kt][jj] = vh;
          wrl[t][kt][jj] = (__bf16)(vr - (float)vh);
        }
    }
    const int ccStep = fw ? -1 : 1;
#pragma unroll
    for (int j = 0; j < 4; ++j) {
      int ro = R0 + hi16 * 4 + j;
      int rr = fh ? 127 - ro : ro;
      int c0 = R0 - ro;
      oidx[j] = ((bb * 128 + rr) * 128 + (fw ? 127 - c0 : c0)) * NG + f * 64 + u;
      int lm = hi16 * 4 + j;
      o_hw[j] = hix(lm + 1, u * 2);
    }
    oStep = ccStep * NG;
    cbase = -hi16 * 4;
    o_hu0 = hix(lo16, hi16 * 16);       // h_up  (buffer row lo16)
    o_hu1 = hix(lo16, 64 + hi16 * 16);
    o_hl0 = hix(lo16 + 1, hi16 * 16);   // h_left (buffer row lo16+1)
    o_hl1 = hix(lo16 + 1, 64 + hi16 * 16);
    o_cu0 = cix(hi16 * 4, u);           // only cross-lane c read
    o_c4 = cix(hi16 * 4 + 4, u);        // only live c write (j==3, hi16<3)
    invBase = (R0 == 0 && lo16 == 0) ? 1.f : (1.f / 3.f);
  } else {
    const float* Wkf = Wk + f * (64 * NG);
#pragma unroll
    for (int t = 0; t < 4; ++t) {
      const float st = (t == 2) ? (2.f * L2E) : L2E;
      bsc[t] = bias[f * NG + t * 64 + u] * st;
#pragma unroll
      for (int kt = 0; kt < 2; ++kt)
#pragma unroll
        for (int jj = 0; jj < 8; ++jj) {
          int k = kt * 32 + hi16 * 8 + jj;
          wkh[t][kt][jj] = (__bf16)(Wkf[k * NG + t * 64 + u] * st);
        }
    }
  }
  const int o_ax0 = hix(lo16, hi16 * 16);
  const int o_ax1 = hix(lo16, 64 + hi16 * 16);

  // ---- helper-wave x addressing ----
  const int ccStepH = fw ? -1 : 1;
  const int rx = R0 + hm0;
  const int rrx = fh ? 127 - rx : rx;
  int cx = R0 - rx;
  int xidx = ((bb * 128 + rrx) * 128 + (fw ? 127 - cx : cx)) * 64 + hq16 * 4;
  const int xStep = ccStepH * 64;
  float4 px;
  bool pxv = false;
  auto ldg = [&]() {
    pxv = ((unsigned)cx <= 127u);
    px = make_float4(0.f, 0.f, 0.f, 0.f);
    if (pxv) px = *(const float4*)(x + xidx);
    xidx += xStep;
    ++cx;
  };
  auto stx = [&](unsigned char* buf) {
    if (pxv) {
      bf16x4 pk;
      pk[0] = (__bf16)px.x; pk[1] = (__bf16)px.y;
      pk[2] = (__bf16)px.z; pk[3] = (__bf16)px.w;
      *(bf16x4*)(buf + hix(hm0, hq16 * 8)) = pk;
    }
  };
  // helper: accA(tile) = x@Wk + b -> zbuf[bi] (conflict-free b128 lanes)
  auto accx = [&](const unsigned char* xp, int bi) {
    bf16x8 a0 = *(const bf16x8*)(xp + o_ax0);
    bf16x8 a1 = *(const bf16x8*)(xp + o_ax1);
    float* zw = &zbuf[bi][0] + (wq * 64 + L) * 4;
#pragma unroll
    for (int t = 0; t < 4; ++t) {
      f32x4 az = (f32x4){bsc[t], bsc[t], bsc[t], bsc[t]};
      az = __builtin_amdgcn_mfma_f32_16x16x32_bf16(a0, wkh[t][0], az, 0, 0, 0);
      az = __builtin_amdgcn_mfma_f32_16x16x32_bf16(a1, wkh[t][1], az, 0, 0, 0);
      *(f32x4*)(zw + t * 1024) = az;
    }
  };

  __syncthreads();  // zero-init visible

  if (!isComp) {
    ldg();                  // px = x(R0)
    stx(&xt[R0 & 1][0]);
    ldg();                  // px = x(R0+1)
  }
  __syncthreads();  // x(R0) visible for accx fragment reads

  if (!isComp) {
    accx(&xt[R0 & 1][0], R0 & 1);  // zbuf[R0&1] = accA(R0)
    stx(&xt[(R0 + 1) & 1][0]);     // stage x(R0+1)
    ldg();                         // px = x(R0+2)
    // pre-loop poll (helper wave 0): tags R0-1 and R0; fold R0-1 into row 0
    if (wq == 0 && ch > 0) {
#pragma unroll
      for (int k = 0; k < 2; ++k) {
        const int q = R0 - 1 + k;
        u64* src = ring + ((linkDn * RDEPTH + (q & (RDEPTH - 1))) << 6) + L;
        u64 v;
        int spin = 0;
        for (;;) {
          v = __hip_atomic_load(src, __ATOMIC_RELAXED, __HIP_MEMORY_SCOPE_AGENT);
          if ((unsigned short)(v >> 48) == (unsigned short)q ||
              spin >= (1 << 22))
            break;
          ++spin;
          __builtin_amdgcn_s_sleep(2);
        }
        *(unsigned short*)(gbh + (q & 7) * 128 + L * 2) =
            (unsigned short)(v >> 32);
        gbc[(q & 7) * 64 + L] = __uint_as_float((unsigned)v);
        if (k == 0) {  // guard tag R0-1 -> row 0 of the "previous" buffers
          *(unsigned short*)(&hbuf[(R0 + 1) & 1][0] + L * 2) =
              (unsigned short)(v >> 32);
          cbuf[(R0 + 1) & 1][L] = __uint_as_float((unsigned)v);
        }
      }
      if (L == 0)
        __hip_atomic_store(&prog[linkDn * 16], R0, __ATOMIC_RELAXED,
                           __HIP_MEMORY_SCOPE_AGENT);
    }
  }
  __syncthreads();

  // ---- rotating state (all threads; uniform) ----
  unsigned char* hW = &hbuf[R0 & 1][0];
  unsigned char* hP = &hbuf[(R0 + 1) & 1][0];
  float* cW = &cbuf[R0 & 1][0];
  float* cP = &cbuf[(R0 + 1) & 1][0];
  int gOff = (R0 & 7) * 128;

  // ---- compute-wave carried state ----
  float hxf0[8], hxf1[8];  // carried h_ul = prev step's h_up, kept in f32
  float cnv[4];            // carried c(d-1)[row lm] (this lane's last cn)
  float puv[4];            // carried c_ul = prev step's c_up
  int gateSeen = 0;
  if (isComp) {
#pragma unroll
    for (int e = 0; e < 8; ++e) { hxf0[e] = 0.f; hxf1[e] = 0.f; }
#pragma unroll
    for (int j = 0; j < 4; ++j) { cnv[j] = 0.f; puv[j] = 0.f; }
    __builtin_amdgcn_s_setprio(1);  // compute waves favored over helpers
  }

  for (int d = R0; d <= D1; ++d) {
    if (isComp) {
      // ---- post-barrier critical region ----
      bf16x8 hu0 = *(const bf16x8*)(hP + o_hu0);
      bf16x8 hu1 = *(const bf16x8*)(hP + o_hu1);
      bf16x8 hl0 = *(const bf16x8*)(hP + o_hl0);
      bf16x8 hl1 = *(const bf16x8*)(hP + o_hl1);
      const float pu0 = cP[o_cu0];
      const float* zb = &zbuf[d & 1][0] + (wq * 64 + L) * 4;
      f32x4 zacc[4];
#pragma unroll
      for (int t = 0; t < 4; ++t) zacc[t] = *(const f32x4*)(zb + t * 1024);

      const bool pub = (ch < NCH - 1) && (d >= R0 + 15);
      if (pub && d >= R0 + 15 + RDEPTH && gateSeen < d - RDEPTH)
        gateSeen = __hip_atomic_load(&prog[linkUp * 16], __ATOMIC_RELAXED,
                                     __HIP_MEMORY_SCOPE_AGENT);

      // h-sum A-fragments; neighbor-count 1/cnt folded into A row scale
      const float inv_a = ((d - R0) == lo16) ? 1.f : invBase;
      bf16x8 ah0, ah1;
#pragma unroll
      for (int e = 0; e < 8; ++e) {
        const float a0 = (float)hu0[e], a1 = (float)hu1[e];
        ah0[e] = (__bf16)(inv_a * (a0 + (float)hl0[e] + hxf0[e]));
        ah1[e] = (__bf16)(inv_a * (a1 + (float)hl1[e] + hxf1[e]));
        hxf0[e] = a0; hxf1[e] = a1;
      }
      float csj[4];
#pragma unroll
      for (int j = 0; j < 4; ++j) {
        const float puj = (j == 0) ? pu0 : cnv[j - 1];
        csj[j] = puj + cnv[j] + puv[j];
        puv[j] = puj;
      }

      // ---- 16 MFMA chained from C=accA: z = accA + (inv*hsum)@Wr(hi+lo)
#pragma unroll
      for (int t = 0; t < 4; ++t)
        zacc[t] = __builtin_amdgcn_mfma_f32_16x16x32_bf16(ah0, wrh[t][0], zacc[t], 0, 0, 0);
#pragma unroll
      for (int t = 0; t < 4; ++t)
        zacc[t] = __builtin_amdgcn_mfma_f32_16x16x32_bf16(ah1, wrh[t][1], zacc[t], 0, 0, 0);
#pragma unroll
      for (int t = 0; t < 4; ++t)
        zacc[t] = __builtin_amdgcn_mfma_f32_16x16x32_bf16(ah0, wrl[t][0], zacc[t], 0, 0, 0);
#pragma unroll
      for (int t = 0; t < 4; ++t)
        zacc[t] = __builtin_amdgcn_mfma_f32_16x16x32_bf16(ah1, wrl[t][1], zacc[t], 0, 0, 0);

      // ---- epilogue: LSTM, publish (top row first), state/out writes ----
#pragma unroll
      for (int jj = 0; jj < 4; ++jj) {
        const int j = 3 - jj;
        const int lm = hi16 * 4 + j;
        const int r = R0 + lm;
        const int cj = cbase - j;
        const bool ok = ((unsigned)cj <= 127u);
        const float inv = (cj == 0 || r == 0) ? 1.f : (1.f / 3.f);
        const float cpj = csj[j] * inv;
        float cn = sigm2(zacc[1][j]) * cpj + sigm2(zacc[0][j]) * tanh2(zacc[2][j]);
        float hn = sigm2(zacc[3][j]) * tanh2(2.f * L2E * cn);
        if (pub && lm == CELLS - 1) {
          if (d >= R0 + 15 + RDEPTH && gateSeen < d - RDEPTH) {  // backstop
            int spin = 0;
            do {
              gateSeen = __hip_atomic_load(&prog[linkUp * 16], __ATOMIC_RELAXED,
                                           __HIP_MEMORY_SCOPE_AGENT);
            } while (gateSeen < d - RDEPTH && ++spin < (1 << 22));
          }
          u64 v = ((u64)(unsigned short)d << 48) | ((u64)f2bfbits(hn) << 32) |
                  (u64)__float_as_uint(cn);
          u64* dst = ring + ((linkUp * RDEPTH + (d & (RDEPTH - 1))) << 6) + u;
          __hip_atomic_store(dst, v, __ATOMIC_RELAXED,
                             __HIP_MEMORY_SCOPE_AGENT);
        }
        cn = ok ? cn : 0.f;
        cnv[j] = cn;
        if (j == 3 && hi16 < 3) cW[o_c4] = cn;  // only row others read
        *(unsigned short*)(hW + o_hw[j]) =
            ok ? f2bfbits(hn) : (unsigned short)0;
        if (ok) out[oidx[j]] = hn;
      }
#pragma unroll
      for (int j = 0; j < 4; ++j) oidx[j] += oStep;
      ++cbase;
    } else {
      // ---- helpers: poll ISSUE -> accx -> guard/stage -> poll RESOLVE ----
      const bool doPoll = (((d - R0) & 1) == 0) && (ch > 0) && (wq == 0);
      u64 pv[3];
      const u64* ps[3];
      bool live[3];
      if (doPoll) {
        const int kk0 = (d == R0) ? 0 : 1;  // first poll also grabs d+1
#pragma unroll
        for (int k = 0; k < 3; ++k) {
          const int q = d + 1 + k;
          live[k] = (k >= kk0) && (q <= R0 + 126);
          ps[k] = ring + ((linkDn * RDEPTH + (q & (RDEPTH - 1))) << 6) + L;
          pv[k] = live[k] ? __hip_atomic_load(ps[k], __ATOMIC_RELAXED,
                                              __HIP_MEMORY_SCOPE_AGENT)
                          : 0;
        }
      }
      accx(&xt[(d + 1) & 1][0], (d + 1) & 1);
      if (wq == 0 && ch > 0) {  // ring guard tag d -> row 0 of write buffers
        *(unsigned short*)(hW + L * 2) =
            *(const unsigned short*)(gbh + gOff + L * 2);
        cW[L] = gbc[(gOff >> 1) + L];
      }
      stx(&xt[d & 1][0]);  // x(d+2)
      ldg();               // px = x(d+3)
      if (doPoll) {
#pragma unroll
        for (int k = 0; k < 3; ++k) {
          if (!live[k]) continue;
          const int q = d + 1 + k;
          int spin = 0;
          while ((unsigned short)(pv[k] >> 48) != (unsigned short)q &&
                 spin < (1 << 22)) {
            ++spin;
            __builtin_amdgcn_s_sleep(1);
            pv[k] = __hip_atomic_load(ps[k], __ATOMIC_RELAXED,
                                      __HIP_MEMORY_SCOPE_AGENT);
          }
          *(unsigned short*)(gbh + (q & 7) * 128 + L * 2) =
              (unsigned short)(pv[k] >> 32);
          gbc[(q & 7) * 64 + L] = __uint_as_float((unsigned)pv[k]);
        }
        if (L == 0)
          __hip_atomic_store(&prog[linkDn * 16], min(d + 3, R0 + 126),
                             __ATOMIC_RELAXED, __HIP_MEMORY_SCOPE_AGENT);
      }
    }

    // rotate buffers (uniform, cheap pointer swaps)
    {
      unsigned char* t1 = hW; hW = hP; hP = t1;
      float* t2 = cW; cW = cP; cP = t2;
      gOff = (gOff + 128) & 1023;
    }
    barrier_lds();  // single barrier: all LDS writes -> next step's reads
  }
}

extern "C" void kernel_launch(void* const* d_in, const int* in_sizes, int n_in,
                              void* d_out, int out_size, void* d_ws, size_t ws_size,
                              hipStream_t stream) {
  const float* x = (const float*)d_in[0];
  const float* Wk = (const float*)d_in[1];
  const float* Wr = (const float*)d_in[2];
  const float* b = (const float*)d_in[3];
  float* out = (float*)d_out;
  // reset ring tags + progress flags every launch (graph-replay determinism)
  hipMemsetAsync(d_ws, 0, PROG_OFF + NLINK * 16 * sizeof(int), stream);
  hipLaunchKernelGGL(mdrnn_kernel, dim3(128), dim3(512), 0, stream, x, Wk, Wr,
                     b, out, (char*)d_ws);
}

// Round 4
// 268.649 us; speedup vs baseline: 1.1858x; 1.1374x over previous
//
#include <hip/hip_runtime.h>

typedef __bf16 bf16x8 __attribute__((ext_vector_type(8)));
typedef __bf16 bf16x4 __attribute__((ext_vector_type(4)));
typedef float f32x4 __attribute__((ext_vector_type(4)));
typedef unsigned long long u64;

#define NCH 8            // row-chunks per recurrence
#define CELLS 16         // rows per chunk
#define NG 256           // 4 gates * 64 units
#define L2E 1.44269504089f
#define RDEPTH 16                       // ring depth (tag mod 16)
#define NLINK (16 * 7)                  // (g, producer ch 0..6)
#define RING_U64 (NLINK * RDEPTH * 64)  // 896 KiB
#define PROG_OFF (RING_U64 * 8)         // byte offset of progress flags

__device__ __forceinline__ unsigned short f2bfbits(float f) {
  __bf16 b = (__bf16)f;
  return __builtin_bit_cast(unsigned short, b);
}
__device__ __forceinline__ float bfbits2f(unsigned short s) {
  return (float)__builtin_bit_cast(__bf16, s);
}
// LDS-only barrier: vmcnt stays in flight (out stores, x prefetch, ring ops)
__device__ __forceinline__ void barrier_lds() {
  asm volatile("s_waitcnt lgkmcnt(0)" ::: "memory");
  __builtin_amdgcn_s_barrier();
}
// 16B-granule XOR swizzle for 128B bf16 rows (row 0 identity -> linear).
__device__ __forceinline__ int hix(int row, int byteoff) {
  return row * 128 + (byteoff ^ ((row & 7) << 4));
}

// ROW-partitioned 2D-LSTM pipeline; WAVE-SPECIALIZED single-barrier step.
// Block = (chunk ch, recurrence g), 512 thr = 8 waves (2/SIMD):
//   waves 0-3 (compute): post-barrier critical region is just
//     {2x ds_read_b128 of PRE-SUMMED, PRE-SCALED A-rows (P), 16 h@Wr MFMA
//     chained from C=accA(prefetched)}. Epilogue: merged-rcp LSTM gates,
//     publish, out stores, then the PRODUCER PRESUM pass: P(d)[r] =
//     s_r * (h[r-1]+h[r]+hprev[r-1]) built from f32 registers (adjacent j)
//     + one 16-lane shuffle (row crossing) + direct gbh/gbc guard reads
//     (row 0), written bf16 to Pbuf; c-path fully register/shuffle-local
//     (cbuf eliminated); zacc for next step prefetched from zbuf at tail.
//   waves 4-7 (helper): accA(d+2)=x@Wk+b (8 MFMA) -> zbuf dbuf; stage
//     x(d+3)->xt tri-buf, prefetch x(d+4). Wave 4: polls tags d+2,d+3
//     every 2 steps, issue-early / resolve-late. No per-step guard copy
//     (folded into compute's presum) -> wave-4 is no longer the straggler.
__global__ __launch_bounds__(512, 1) void mdrnn_kernel(
    const float* __restrict__ x, const float* __restrict__ Wk,
    const float* __restrict__ Wr, const float* __restrict__ bias,
    float* __restrict__ out, char* __restrict__ ws) {
  __shared__ __align__(16) unsigned char xt[3][CELLS * 128];    // 6 KiB
  __shared__ __align__(16) unsigned char Pbuf[2][CELLS * 128];  // 4 KiB
  __shared__ __align__(16) unsigned char gbh[8 * 128];          // 1 KiB
  __shared__ __align__(16) float gbc[8 * 64];                   // 2 KiB
  __shared__ __align__(16) float zbuf[2][4096];                 // 32 KiB

  u64* __restrict__ ring = (u64*)ws;
  int* __restrict__ prog = (int*)(ws + PROG_OFF);  // 16-int (64B) stride

  const int tid = threadIdx.x;
  const bool isComp = (tid < 256);
  const int L = tid & 63;
  const int lo16 = L & 15;
  const int hi16 = L >> 4;
  const int wq = (tid >> 6) & 3;     // wave id within compute/helper group
  const int u = wq * 16 + lo16;      // unit-group index (both roles)
  const int hm0 = (tid >> 4) & 15;   // helper: staged row
  const int hq16 = tid & 15;         // helper: channel quad

  const int ch = blockIdx.x >> 4;   // bx%8 == g%8 -> chain on one XCD
  const int g = blockIdx.x & 15;
  const int f = g >> 2;
  const int bb = g & 3;
  const int fh = (f >> 1) & 1;
  const int fw = f & 1;
  const int R0 = ch * CELLS;
  const int D1 = R0 + 142;
  const int linkDn = g * 7 + ch - 1;
  const int linkUp = g * 7 + ch;

  for (int i = tid; i < 3 * CELLS * 32; i += 512) ((int*)xt)[i] = 0;
  for (int i = tid; i < 2 * CELLS * 32; i += 512) ((int*)Pbuf)[i] = 0;
  for (int i = tid; i < 8 * 32; i += 512) ((int*)gbh)[i] = 0;
  for (int i = tid; i < 8 * 64; i += 512) gbc[i] = 0.f;

  // ---- per-role constants ----
  float bsc[4] = {0.f, 0.f, 0.f, 0.f};
  bf16x8 wkh[4][2], wrh[4][2], wrl[4][2];
  int oidx[4];
  int oStep = 0, cbase = 0;
  int o_ph0 = 0, o_ph1 = 0;
  int o_pw[4] = {0, 0, 0, 0};
  if (isComp) {
    const float* Wrf = Wr + f * (64 * NG);
#pragma unroll
    for (int t = 0; t < 4; ++t) {
      const float st = (t == 2) ? (2.f * L2E) : L2E;
#pragma unroll
      for (int kt = 0; kt < 2; ++kt)
#pragma unroll
        for (int jj = 0; jj < 8; ++jj) {
          int k = kt * 32 + hi16 * 8 + jj;
          float vr = Wrf[k * NG + t * 64 + u] * st;
          __bf16 vh = (__bf16)vr;
          wrh[t][kt][jj] = vh;
          wrl[t][kt][jj] = (__bf16)(vr - (float)vh);
        }
    }
    const int ccStep = fw ? -1 : 1;
#pragma unroll
    for (int j = 0; j < 4; ++j) {
      int ro = R0 + hi16 * 4 + j;
      int rr = fh ? 127 - ro : ro;
      int c0 = R0 - ro;
      oidx[j] = ((bb * 128 + rr) * 128 + (fw ? 127 - c0 : c0)) * NG + f * 64 + u;
      o_pw[j] = hix(hi16 * 4 + j, u * 2);
    }
    oStep = ccStep * NG;
    cbase = -hi16 * 4;
    o_ph0 = hix(lo16, hi16 * 16);       // presummed A-row lo16, k 0..31
    o_ph1 = hix(lo16, 64 + hi16 * 16);  // k 32..63
  } else {
    const float* Wkf = Wk + f * (64 * NG);
#pragma unroll
    for (int t = 0; t < 4; ++t) {
      const float st = (t == 2) ? (2.f * L2E) : L2E;
      bsc[t] = bias[f * NG + t * 64 + u] * st;
#pragma unroll
      for (int kt = 0; kt < 2; ++kt)
#pragma unroll
        for (int jj = 0; jj < 8; ++jj) {
          int k = kt * 32 + hi16 * 8 + jj;
          wkh[t][kt][jj] = (__bf16)(Wkf[k * NG + t * 64 + u] * st);
        }
    }
  }
  const int o_ax0 = hix(lo16, hi16 * 16);
  const int o_ax1 = hix(lo16, 64 + hi16 * 16);

  // ---- helper-wave x addressing ----
  const int ccStepH = fw ? -1 : 1;
  const int rx = R0 + hm0;
  const int rrx = fh ? 127 - rx : rx;
  int cx = R0 - rx;
  int xidx = ((bb * 128 + rrx) * 128 + (fw ? 127 - cx : cx)) * 64 + hq16 * 4;
  const int xStep = ccStepH * 64;
  float4 px;
  bool pxv = false;
  auto ldg = [&]() {
    pxv = ((unsigned)cx <= 127u);
    px = make_float4(0.f, 0.f, 0.f, 0.f);
    if (pxv) px = *(const float4*)(x + xidx);
    xidx += xStep;
    ++cx;
  };
  auto stx = [&](unsigned char* buf) {
    if (pxv) {
      bf16x4 pk;
      pk[0] = (__bf16)px.x; pk[1] = (__bf16)px.y;
      pk[2] = (__bf16)px.z; pk[3] = (__bf16)px.w;
      *(bf16x4*)(buf + hix(hm0, hq16 * 8)) = pk;
    }
  };
  // helper: accA(tile) = x@Wk + b -> zbuf[bi] (conflict-free b128 lanes)
  auto accx = [&](const unsigned char* xp, int bi) {
    bf16x8 a0 = *(const bf16x8*)(xp + o_ax0);
    bf16x8 a1 = *(const bf16x8*)(xp + o_ax1);
    float* zw = &zbuf[bi][0] + (wq * 64 + L) * 4;
#pragma unroll
    for (int t = 0; t < 4; ++t) {
      f32x4 az = (f32x4){bsc[t], bsc[t], bsc[t], bsc[t]};
      az = __builtin_amdgcn_mfma_f32_16x16x32_bf16(a0, wkh[t][0], az, 0, 0, 0);
      az = __builtin_amdgcn_mfma_f32_16x16x32_bf16(a1, wkh[t][1], az, 0, 0, 0);
      *(f32x4*)(zw + t * 1024) = az;
    }
  };

  __syncthreads();  // S0: zero-init visible

  if (!isComp) {
    ldg();                       // px = x(R0)
    stx(&xt[R0 % 3][0]);
    ldg();                       // px = x(R0+1)
  }
  __syncthreads();  // S1: xt(R0) visible

  if (!isComp) {
    stx(&xt[(R0 + 1) % 3][0]);   // stage x(R0+1)
    ldg();                       // px = x(R0+2)
    accx(&xt[R0 % 3][0], R0 & 1);
    // pre-loop poll (wave 4): tags R0-1 and R0; P-init row 0 from tag R0-1
    if (wq == 0 && ch > 0) {
#pragma unroll
      for (int k = 0; k < 2; ++k) {
        const int q = R0 - 1 + k;
        u64* src = ring + ((linkDn * RDEPTH + (q & (RDEPTH - 1))) << 6) + L;
        u64 v;
        int spin = 0;
        for (;;) {
          v = __hip_atomic_load(src, __ATOMIC_RELAXED, __HIP_MEMORY_SCOPE_AGENT);
          if ((unsigned short)(v >> 48) == (unsigned short)q ||
              spin >= (1 << 22))
            break;
          ++spin;
          __builtin_amdgcn_s_sleep(2);
        }
        *(unsigned short*)(gbh + (q & 7) * 128 + L * 2) =
            (unsigned short)(v >> 32);
        gbc[(q & 7) * 64 + L] = __uint_as_float((unsigned)v);
        if (k == 0)  // P(R0-1)[row0] = guard h (scale 1; rest stays zero)
          *(unsigned short*)(&Pbuf[(R0 + 1) & 1][0] + L * 2) =
              (unsigned short)(v >> 32);
      }
      if (L == 0)
        __hip_atomic_store(&prog[linkDn * 16], R0, __ATOMIC_RELAXED,
                           __HIP_MEMORY_SCOPE_AGENT);
    }
  }
  __syncthreads();  // S2: xt(R0+1), zbuf(R0), gbh/gbc, P-init visible

  // ---- compute-wave carried state ----
  f32x4 zacc[4];
  float hnprev[4];  // this lane's h(d-1)[rows lm] (masked)
  float cnv[4];     // this lane's c(d-1)[rows lm] (masked) -- internal use
  float csj[4];     // presummed c for the CURRENT step
  float puv[4];     // carried c_ul = prev step's c_up
  int gateSeen = 0;
  if (isComp) {
    const float* zb = &zbuf[R0 & 1][0] + (wq * 64 + L) * 4;
#pragma unroll
    for (int t = 0; t < 4; ++t) zacc[t] = *(const f32x4*)(zb + t * 1024);
    const float cu0 = gbc[((R0 - 1) & 7) * 64 + u];  // zero for ch==0
#pragma unroll
    for (int j = 0; j < 4; ++j) {
      const float ci = (hi16 == 0 && j == 0) ? cu0 : 0.f;
      csj[j] = ci;
      puv[j] = ci;
      hnprev[j] = 0.f;
      cnv[j] = 0.f;
    }
    __builtin_amdgcn_s_setprio(1);  // compute waves favored over helpers
  } else {
    accx(&xt[(R0 + 1) % 3][0], (R0 + 1) & 1);
    stx(&xt[(R0 + 2) % 3][0]);   // stage x(R0+2)
    ldg();                       // px = x(R0+3)
  }
  __syncthreads();  // S3: zbuf(R0+1), xt(R0+2) visible

  // rotating pointers (uniform)
  unsigned char* Pc = &Pbuf[R0 & 1][0];        // written this step
  unsigned char* Pp = &Pbuf[(R0 + 1) & 1][0];  // read this step
  unsigned char* xA = &xt[(R0 + 2) % 3][0];    // accx read (x(d+2))
  unsigned char* xB = &xt[R0 % 3][0];          // stx write (x(d+3))
  unsigned char* xC = &xt[(R0 + 1) % 3][0];

  for (int d = R0; d <= D1; ++d) {
    if (isComp) {
      // ---- post-barrier critical region: 2 loads -> 16 MFMA ----
      bf16x8 pa0 = *(const bf16x8*)(Pp + o_ph0);
      bf16x8 pa1 = *(const bf16x8*)(Pp + o_ph1);
#pragma unroll
      for (int t = 0; t < 4; ++t)
        zacc[t] = __builtin_amdgcn_mfma_f32_16x16x32_bf16(pa0, wrh[t][0], zacc[t], 0, 0, 0);
#pragma unroll
      for (int t = 0; t < 4; ++t)
        zacc[t] = __builtin_amdgcn_mfma_f32_16x16x32_bf16(pa1, wrh[t][1], zacc[t], 0, 0, 0);
#pragma unroll
      for (int t = 0; t < 4; ++t)
        zacc[t] = __builtin_amdgcn_mfma_f32_16x16x32_bf16(pa0, wrl[t][0], zacc[t], 0, 0, 0);
#pragma unroll
      for (int t = 0; t < 4; ++t)
        zacc[t] = __builtin_amdgcn_mfma_f32_16x16x32_bf16(pa1, wrl[t][1], zacc[t], 0, 0, 0);

      const bool pub = (ch < NCH - 1) && (d >= R0 + 15);
      if (pub && d >= R0 + 15 + RDEPTH && gateSeen < d - RDEPTH)
        gateSeen = __hip_atomic_load(&prog[linkUp * 16], __ATOMIC_RELAXED,
                                     __HIP_MEMORY_SCOPE_AGENT);

      // guard values for presum/c-pass (tags d, d-1; stale slots only feed
      // masked-out rows). Row-0 swizzle of gbh rows is identity (linear).
      const float gh1 = bfbits2f(*(const unsigned short*)(gbh + (d & 7) * 128 + u * 2));
      const float gh2 = bfbits2f(*(const unsigned short*)(gbh + ((d - 1) & 7) * 128 + u * 2));
      const float gc1 = gbc[(d & 7) * 64 + u];

      // ---- epilogue: merged-rcp LSTM gates, publish, out stores ----
      float hcur[4], cnew[4];
#pragma unroll
      for (int jj = 0; jj < 4; ++jj) {
        const int j = 3 - jj;
        const int lm = hi16 * 4 + j;
        const int cj = cbase - j;
        const bool ok = ((unsigned)cj <= 127u);
        const float inv = (cj == 0 || (R0 + lm) == 0) ? 1.f : (1.f / 3.f);
        const float cpj = csj[j] * inv;
        const float e1 = __builtin_amdgcn_exp2f(-zacc[1][j]);  // zf
        const float e2 = __builtin_amdgcn_exp2f(-zacc[0][j]);  // zi
        const float e3 = __builtin_amdgcn_exp2f(zacc[2][j]);   // zg
        float cn = cpj * __builtin_amdgcn_rcpf(1.f + e1) +
                   (e3 - 1.f) * __builtin_amdgcn_rcpf((1.f + e2) * (1.f + e3));
        const float e4 = __builtin_amdgcn_exp2f(-zacc[3][j]);  // zo
        const float e5 = __builtin_amdgcn_exp2f(2.f * L2E * cn);
        float hn = (e5 - 1.f) * __builtin_amdgcn_rcpf((1.f + e4) * (1.f + e5));
        if (pub && lm == CELLS - 1) {
          if (d >= R0 + 15 + RDEPTH && gateSeen < d - RDEPTH) {  // backstop
            int spin = 0;
            do {
              gateSeen = __hip_atomic_load(&prog[linkUp * 16], __ATOMIC_RELAXED,
                                           __HIP_MEMORY_SCOPE_AGENT);
            } while (gateSeen < d - RDEPTH && ++spin < (1 << 22));
          }
          u64 v = ((u64)(unsigned short)d << 48) | ((u64)f2bfbits(hn) << 32) |
                  (u64)__float_as_uint(cn);
          u64* dst = ring + ((linkUp * RDEPTH + (d & (RDEPTH - 1))) << 6) + u;
          __hip_atomic_store(dst, v, __ATOMIC_RELAXED,
                             __HIP_MEMORY_SCOPE_AGENT);
        }
        hn = ok ? hn : 0.f;
        cn = ok ? cn : 0.f;
        hcur[j] = hn;
        cnew[j] = cn;
        if (ok) out[oidx[j]] = hn;
      }

      // ---- producer presum pass: P(d) rows + csj for step d+1 ----
      const unsigned pk =
          ((unsigned)f2bfbits(hcur[3]) << 16) | f2bfbits(hnprev[3]);
      const unsigned pku = __shfl((int)pk, (L - 16) & 63);
      const float up_h = bfbits2f((unsigned short)(pku >> 16));
      const float up_hp = bfbits2f((unsigned short)(pku & 0xffff));
      const float up_c = __shfl(cnew[3], (L - 16) & 63);
#pragma unroll
      for (int j = 0; j < 4; ++j) {
        const float hup = j ? hcur[j - 1] : (hi16 ? up_h : gh1);
        const float hulp = j ? hnprev[j - 1] : (hi16 ? up_hp : gh2);
        const float sPj =
            ((cbase + 1 == j) || (R0 == 0 && hi16 == 0 && j == 0))
                ? 1.f : (1.f / 3.f);
        *(unsigned short*)(Pc + o_pw[j]) =
            f2bfbits(sPj * (hup + hcur[j] + hulp));
        const float cun = j ? cnew[j - 1] : (hi16 ? up_c : gc1);
        csj[j] = cun + cnew[j] + puv[j];
        puv[j] = cun;
      }
#pragma unroll
      for (int j = 0; j < 4; ++j) {
        hnprev[j] = hcur[j];
        cnv[j] = cnew[j];
        oidx[j] += oStep;
      }
      ++cbase;

      // ---- tail: prefetch accA(d+1) from zbuf (written at step d-1) ----
      const float* zb = &zbuf[(d + 1) & 1][0] + (wq * 64 + L) * 4;
#pragma unroll
      for (int t = 0; t < 4; ++t) zacc[t] = *(const f32x4*)(zb + t * 1024);
    } else {
      // ---- helpers: poll ISSUE -> accx(d+2) -> stage -> poll RESOLVE ----
      const bool doPoll = (((d - R0) & 1) == 0) && (ch > 0) && (wq == 0);
      u64 pv[3];
      const u64* ps[3];
      bool live[3];
      if (doPoll) {
        const int kk0 = (d == R0) ? 0 : 1;  // first poll also grabs d+1
#pragma unroll
        for (int k = 0; k < 3; ++k) {
          const int q = d + 1 + k;
          live[k] = (k >= kk0) && (q <= R0 + 126);
          ps[k] = ring + ((linkDn * RDEPTH + (q & (RDEPTH - 1))) << 6) + L;
          pv[k] = live[k] ? __hip_atomic_load(ps[k], __ATOMIC_RELAXED,
                                              __HIP_MEMORY_SCOPE_AGENT)
                          : 0;
        }
      }
      accx(xA, (d + 2) & 1);
      stx(xB);  // x(d+3)
      ldg();    // px = x(d+4)
      if (doPoll) {
#pragma unroll
        for (int k = 0; k < 3; ++k) {
          if (!live[k]) continue;
          const int q = d + 1 + k;
          int spin = 0;
          while ((unsigned short)(pv[k] >> 48) != (unsigned short)q &&
                 spin < (1 << 22)) {
            ++spin;
            __builtin_amdgcn_s_sleep(1);
            pv[k] = __hip_atomic_load(ps[k], __ATOMIC_RELAXED,
                                      __HIP_MEMORY_SCOPE_AGENT);
          }
          *(unsigned short*)(gbh + (q & 7) * 128 + L * 2) =
              (unsigned short)(pv[k] >> 32);
          gbc[(q & 7) * 64 + L] = __uint_as_float((unsigned)pv[k]);
        }
        if (L == 0)
          __hip_atomic_store(&prog[linkDn * 16], min(d + 3, R0 + 126),
                             __ATOMIC_RELAXED, __HIP_MEMORY_SCOPE_AGENT);
      }
    }

    // rotate buffers (uniform, cheap pointer swaps)
    {
      unsigned char* t0 = xA; xA = xB; xB = xC; xC = t0;
      unsigned char* t1 = Pc; Pc = Pp; Pp = t1;
    }
    barrier_lds();  // single barrier: all LDS writes -> next step's reads
  }
}

extern "C" void kernel_launch(void* const* d_in, const int* in_sizes, int n_in,
                              void* d_out, int out_size, void* d_ws, size_t ws_size,
                              hipStream_t stream) {
  const float* x = (const float*)d_in[0];
  const float* Wk = (const float*)d_in[1];
  const float* Wr = (const float*)d_in[2];
  const float* b = (const float*)d_in[3];
  float* out = (float*)d_out;
  // reset ring tags + progress flags every launch (graph-replay determinism)
  hipMemsetAsync(d_ws, 0, PROG_OFF + NLINK * 16 * sizeof(int), stream);
  hipLaunchKernelGGL(mdrnn_kernel, dim3(128), dim3(512), 0, stream, x, Wk, Wr,
                     b, out, (char*)d_ws);
}

// Round 5
// 260.720 us; speedup vs baseline: 1.2219x; 1.0304x over previous
//
#include <hip/hip_runtime.h>

typedef __bf16 bf16x8 __attribute__((ext_vector_type(8)));
typedef __bf16 bf16x4 __attribute__((ext_vector_type(4)));
typedef float f32x4 __attribute__((ext_vector_type(4)));
typedef unsigned long long u64;

#define NCH 8            // row-chunks per recurrence
#define CELLS 16         // rows per chunk
#define NG 256           // 4 gates * 64 units
#define L2E 1.44269504089f
#define RDEPTH 16                       // ring depth (tag mod 16)
#define NLINK (16 * 7)                  // (g, producer ch 0..6)
#define RING_U64 (NLINK * RDEPTH * 64)  // 896 KiB
#define PROG_OFF (RING_U64 * 8)         // byte offset of progress flags

__device__ __forceinline__ unsigned short f2bfbits(float f) {
  __bf16 b = (__bf16)f;
  return __builtin_bit_cast(unsigned short, b);
}
__device__ __forceinline__ float bfbits2f(unsigned short s) {
  return (float)__builtin_bit_cast(__bf16, s);
}
// LDS-only barrier: vmcnt stays in flight (out stores, x prefetch, ring ops)
__device__ __forceinline__ void barrier_lds() {
  asm volatile("s_waitcnt lgkmcnt(0)" ::: "memory");
  __builtin_amdgcn_s_barrier();
}
// 16B-granule XOR swizzle for 128B bf16 rows (row 0 identity -> linear).
__device__ __forceinline__ int hix(int row, int byteoff) {
  return row * 128 + (byteoff ^ ((row & 7) << 4));
}

// ROW-partitioned 2D-LSTM pipeline; WAVE-SPECIALIZED single-barrier step.
// Block = (chunk ch, recurrence g), 512 thr = 8 waves (2/SIMD):
//   waves 0-3 (compute): {2x ds_read_b128 of pre-summed A-rows (P) + guard
//     reads, 16 h@Wr MFMA chained from C=accA(prefetched), LSTM epilogue
//     (j=3 first -> pubbuf drop + early shuffles), producer presum pass,
//     zacc prefetch}. NO publish/gate/prog on compute waves.
//   waves 4-7 (helper): accA(d+2)=x@Wk+b (8 MFMA) -> zbuf dbuf; stage
//     x(d+3)->xt tri-buf, prefetch x(d+4).
//     wave 4: publishes tag d-1 from pubbuf (ds_read_b64 + atomic store;
//       ring-wrap gate vs downstream prog, RDEPTH=16 => never binds).
//     waves 4/5 alternate by step parity: resolve ONE ring tag d+3
//       (issue-early at step top, resolve-late after accx/stage), write
//       gbh/gbc, update prog. Parity => disjoint gbh slots, no races.
__global__ __launch_bounds__(512, 1) void mdrnn_kernel(
    const float* __restrict__ x, const float* __restrict__ Wk,
    const float* __restrict__ Wr, const float* __restrict__ bias,
    float* __restrict__ out, char* __restrict__ ws) {
  __shared__ __align__(16) unsigned char xt[3][CELLS * 128];    // 6 KiB
  __shared__ __align__(16) unsigned char Pbuf[2][CELLS * 128];  // 4 KiB
  __shared__ __align__(16) unsigned char gbh[8 * 128];          // 1 KiB
  __shared__ __align__(16) float gbc[8 * 64];                   // 2 KiB
  __shared__ __align__(16) float zbuf[2][4096];                 // 32 KiB
  __shared__ __align__(16) u64 pubbuf[2][64];                   // 1 KiB

  u64* __restrict__ ring = (u64*)ws;
  int* __restrict__ prog = (int*)(ws + PROG_OFF);  // 16-int (64B) stride

  const int tid = threadIdx.x;
  const bool isComp = (tid < 256);
  const int L = tid & 63;
  const int lo16 = L & 15;
  const int hi16 = L >> 4;
  const int wq = (tid >> 6) & 3;     // wave id within compute/helper group
  const int u = wq * 16 + lo16;      // unit-group index (both roles)
  const int hm0 = (tid >> 4) & 15;   // helper: staged row
  const int hq16 = tid & 15;         // helper: channel quad

  const int ch = blockIdx.x >> 4;   // bx%8 == g%8 -> chain on one XCD
  const int g = blockIdx.x & 15;
  const int f = g >> 2;
  const int bb = g & 3;
  const int fh = (f >> 1) & 1;
  const int fw = f & 1;
  const int R0 = ch * CELLS;
  const int D1 = R0 + 142;
  const int linkDn = g * 7 + ch - 1;
  const int linkUp = g * 7 + ch;

  for (int i = tid; i < 3 * CELLS * 32; i += 512) ((int*)xt)[i] = 0;
  for (int i = tid; i < 2 * CELLS * 32; i += 512) ((int*)Pbuf)[i] = 0;
  for (int i = tid; i < 8 * 32; i += 512) ((int*)gbh)[i] = 0;
  for (int i = tid; i < 8 * 64; i += 512) gbc[i] = 0.f;

  // ---- per-role constants ----
  float bsc[4] = {0.f, 0.f, 0.f, 0.f};
  bf16x8 wkh[4][2], wrh[4][2], wrl[4][2];
  int oidx[4];
  int oStep = 0, cbase = 0;
  int o_ph0 = 0, o_ph1 = 0;
  int o_pw[4] = {0, 0, 0, 0};
  if (isComp) {
    const float* Wrf = Wr + f * (64 * NG);
#pragma unroll
    for (int t = 0; t < 4; ++t) {
      const float st = (t == 2) ? (2.f * L2E) : L2E;
#pragma unroll
      for (int kt = 0; kt < 2; ++kt)
#pragma unroll
        for (int jj = 0; jj < 8; ++jj) {
          int k = kt * 32 + hi16 * 8 + jj;
          float vr = Wrf[k * NG + t * 64 + u] * st;
          __bf16 vh = (__bf16)vr;
          wrh[t][kt][jj] = vh;
          wrl[t][kt][jj] = (__bf16)(vr - (float)vh);
        }
    }
    const int ccStep = fw ? -1 : 1;
#pragma unroll
    for (int j = 0; j < 4; ++j) {
      int ro = R0 + hi16 * 4 + j;
      int rr = fh ? 127 - ro : ro;
      int c0 = R0 - ro;
      oidx[j] = ((bb * 128 + rr) * 128 + (fw ? 127 - c0 : c0)) * NG + f * 64 + u;
      o_pw[j] = hix(hi16 * 4 + j, u * 2);
    }
    oStep = ccStep * NG;
    cbase = -hi16 * 4;
    o_ph0 = hix(lo16, hi16 * 16);       // presummed A-row lo16, k 0..31
    o_ph1 = hix(lo16, 64 + hi16 * 16);  // k 32..63
  } else {
    const float* Wkf = Wk + f * (64 * NG);
#pragma unroll
    for (int t = 0; t < 4; ++t) {
      const float st = (t == 2) ? (2.f * L2E) : L2E;
      bsc[t] = bias[f * NG + t * 64 + u] * st;
#pragma unroll
      for (int kt = 0; kt < 2; ++kt)
#pragma unroll
        for (int jj = 0; jj < 8; ++jj) {
          int k = kt * 32 + hi16 * 8 + jj;
          wkh[t][kt][jj] = (__bf16)(Wkf[k * NG + t * 64 + u] * st);
        }
    }
  }
  const int o_ax0 = hix(lo16, hi16 * 16);
  const int o_ax1 = hix(lo16, 64 + hi16 * 16);

  // ---- helper-wave x addressing ----
  const int ccStepH = fw ? -1 : 1;
  const int rx = R0 + hm0;
  const int rrx = fh ? 127 - rx : rx;
  int cx = R0 - rx;
  int xidx = ((bb * 128 + rrx) * 128 + (fw ? 127 - cx : cx)) * 64 + hq16 * 4;
  const int xStep = ccStepH * 64;
  float4 px;
  bool pxv = false;
  auto ldg = [&]() {
    pxv = ((unsigned)cx <= 127u);
    px = make_float4(0.f, 0.f, 0.f, 0.f);
    if (pxv) px = *(const float4*)(x + xidx);
    xidx += xStep;
    ++cx;
  };
  auto stx = [&](unsigned char* buf) {
    if (pxv) {
      bf16x4 pk;
      pk[0] = (__bf16)px.x; pk[1] = (__bf16)px.y;
      pk[2] = (__bf16)px.z; pk[3] = (__bf16)px.w;
      *(bf16x4*)(buf + hix(hm0, hq16 * 8)) = pk;
    }
  };
  // helper: accA(tile) = x@Wk + b -> zbuf[bi] (conflict-free b128 lanes)
  auto accx = [&](const unsigned char* xp, int bi) {
    bf16x8 a0 = *(const bf16x8*)(xp + o_ax0);
    bf16x8 a1 = *(const bf16x8*)(xp + o_ax1);
    float* zw = &zbuf[bi][0] + (wq * 64 + L) * 4;
#pragma unroll
    for (int t = 0; t < 4; ++t) {
      f32x4 az = (f32x4){bsc[t], bsc[t], bsc[t], bsc[t]};
      az = __builtin_amdgcn_mfma_f32_16x16x32_bf16(a0, wkh[t][0], az, 0, 0, 0);
      az = __builtin_amdgcn_mfma_f32_16x16x32_bf16(a1, wkh[t][1], az, 0, 0, 0);
      *(f32x4*)(zw + t * 1024) = az;
    }
  };

  __syncthreads();  // S0: zero-init visible

  if (!isComp) {
    ldg();                       // px = x(R0)
    stx(&xt[R0 % 3][0]);
    ldg();                       // px = x(R0+1)
  }
  __syncthreads();  // S1: xt(R0) visible

  if (!isComp) {
    stx(&xt[(R0 + 1) % 3][0]);   // stage x(R0+1)
    ldg();                       // px = x(R0+2)
    accx(&xt[R0 % 3][0], R0 & 1);
    // pre-loop poll (wave 4): tags R0-1..R0+2; P-init row 0 from tag R0-1
    if (wq == 0 && ch > 0) {
#pragma unroll
      for (int k = 0; k < 4; ++k) {
        const int q = R0 - 1 + k;
        u64* src = ring + ((linkDn * RDEPTH + (q & (RDEPTH - 1))) << 6) + L;
        u64 v;
        int spin = 0;
        for (;;) {
          v = __hip_atomic_load(src, __ATOMIC_RELAXED, __HIP_MEMORY_SCOPE_AGENT);
          if ((unsigned short)(v >> 48) == (unsigned short)q ||
              spin >= (1 << 22))
            break;
          ++spin;
          __builtin_amdgcn_s_sleep(2);
        }
        *(unsigned short*)(gbh + (q & 7) * 128 + L * 2) =
            (unsigned short)(v >> 32);
        gbc[(q & 7) * 64 + L] = __uint_as_float((unsigned)v);
        if (k == 0)  // P(R0-1)[row0] = guard h (scale 1; rest stays zero)
          *(unsigned short*)(&Pbuf[(R0 + 1) & 1][0] + L * 2) =
              (unsigned short)(v >> 32);
      }
      if (L == 0)
        __hip_atomic_store(&prog[linkDn * 16], R0 + 2, __ATOMIC_RELAXED,
                           __HIP_MEMORY_SCOPE_AGENT);
    }
  }
  __syncthreads();  // S2: xt(R0+1), zbuf(R0), gbh/gbc, P-init visible

  // ---- compute-wave carried state ----
  f32x4 zacc[4];
  float hnprev[4];  // this lane's h(d-1)[rows lm] (masked)
  float csj[4];     // presummed c for the CURRENT step
  float puv[4];     // carried c_ul = prev step's c_up
  int gateSeen = 0;  // helper wave 4 only
  if (isComp) {
    const float* zb = &zbuf[R0 & 1][0] + (wq * 64 + L) * 4;
#pragma unroll
    for (int t = 0; t < 4; ++t) zacc[t] = *(const f32x4*)(zb + t * 1024);
    const float cu0 = gbc[((R0 - 1) & 7) * 64 + u];  // zero for ch==0
#pragma unroll
    for (int j = 0; j < 4; ++j) {
      const float ci = (hi16 == 0 && j == 0) ? cu0 : 0.f;
      csj[j] = ci;
      puv[j] = ci;
      hnprev[j] = 0.f;
    }
    __builtin_amdgcn_s_setprio(1);  // compute waves favored over helpers
  } else {
    accx(&xt[(R0 + 1) % 3][0], (R0 + 1) & 1);
    stx(&xt[(R0 + 2) % 3][0]);   // stage x(R0+2)
    ldg();                       // px = x(R0+3)
  }
  __syncthreads();  // S3: zbuf(R0+1), xt(R0+2) visible

  // rotating pointers (uniform)
  unsigned char* Pc = &Pbuf[R0 & 1][0];        // written this step
  unsigned char* Pp = &Pbuf[(R0 + 1) & 1][0];  // read this step
  unsigned char* xA = &xt[(R0 + 2) % 3][0];    // accx read (x(d+2))
  unsigned char* xB = &xt[R0 % 3][0];          // stx write (x(d+3))
  unsigned char* xC = &xt[(R0 + 1) % 3][0];

  for (int d = R0; d <= D1; ++d) {
    if (isComp) {
      // ---- post-barrier critical region: 2 loads -> 16 MFMA ----
      bf16x8 pa0 = *(const bf16x8*)(Pp + o_ph0);
      bf16x8 pa1 = *(const bf16x8*)(Pp + o_ph1);
      // guard reads hoisted pre-MFMA (latency hides under MFMAs); row-0
      // swizzle of gbh rows is identity (linear). Stale slots only feed
      // masked-out rows.
      const float gh1 = bfbits2f(*(const unsigned short*)(gbh + (d & 7) * 128 + u * 2));
      const float gh2 = bfbits2f(*(const unsigned short*)(gbh + ((d - 1) & 7) * 128 + u * 2));
      const float gc1 = gbc[(d & 7) * 64 + u];
#pragma unroll
      for (int t = 0; t < 4; ++t)
        zacc[t] = __builtin_amdgcn_mfma_f32_16x16x32_bf16(pa0, wrh[t][0], zacc[t], 0, 0, 0);
#pragma unroll
      for (int t = 0; t < 4; ++t)
        zacc[t] = __builtin_amdgcn_mfma_f32_16x16x32_bf16(pa1, wrh[t][1], zacc[t], 0, 0, 0);
#pragma unroll
      for (int t = 0; t < 4; ++t)
        zacc[t] = __builtin_amdgcn_mfma_f32_16x16x32_bf16(pa0, wrl[t][0], zacc[t], 0, 0, 0);
#pragma unroll
      for (int t = 0; t < 4; ++t)
        zacc[t] = __builtin_amdgcn_mfma_f32_16x16x32_bf16(pa1, wrl[t][1], zacc[t], 0, 0, 0);

      const bool pubW = (ch < NCH - 1) && (d >= R0 + 15);

      // ---- epilogue: j=3 first (feeds pubbuf + cross-row shuffles) ----
      float hcur[4], cnew[4];
      {
        const int lm = hi16 * 4 + 3;
        const int cj = cbase - 3;
        const bool ok = ((unsigned)cj <= 127u);
        const float inv = (cj == 0 || (R0 + lm) == 0) ? 1.f : (1.f / 3.f);
        const float cpj = csj[3] * inv;
        const float e1 = __builtin_amdgcn_exp2f(-zacc[1][3]);  // zf
        const float e2 = __builtin_amdgcn_exp2f(-zacc[0][3]);  // zi
        const float e3 = __builtin_amdgcn_exp2f(zacc[2][3]);   // zg
        float cn = cpj * __builtin_amdgcn_rcpf(1.f + e1) +
                   (e3 - 1.f) * __builtin_amdgcn_rcpf((1.f + e2) * (1.f + e3));
        const float e4 = __builtin_amdgcn_exp2f(-zacc[3][3]);  // zo
        const float e5 = __builtin_amdgcn_exp2f(2.f * L2E * cn);
        float hn = (e5 - 1.f) * __builtin_amdgcn_rcpf((1.f + e4) * (1.f + e5));
        if (pubW && lm == CELLS - 1)  // raw (unmasked) values, as before
          pubbuf[d & 1][u] = ((u64)(unsigned short)d << 48) |
                             ((u64)f2bfbits(hn) << 32) |
                             (u64)__float_as_uint(cn);
        hn = ok ? hn : 0.f;
        cn = ok ? cn : 0.f;
        hcur[3] = hn;
        cnew[3] = cn;
        if (ok) out[oidx[3]] = hn;
      }
      // issue cross-row shuffles early (hide ds_bpermute under j=2..0)
      const unsigned pk =
          ((unsigned)f2bfbits(hcur[3]) << 16) | f2bfbits(hnprev[3]);
      const unsigned pku = __shfl((int)pk, (L - 16) & 63);
      const float up_c = __shfl(cnew[3], (L - 16) & 63);
#pragma unroll
      for (int jj = 0; jj < 3; ++jj) {
        const int j = 2 - jj;
        const int lm = hi16 * 4 + j;
        const int cj = cbase - j;
        const bool ok = ((unsigned)cj <= 127u);
        const float inv = (cj == 0 || (R0 + lm) == 0) ? 1.f : (1.f / 3.f);
        const float cpj = csj[j] * inv;
        const float e1 = __builtin_amdgcn_exp2f(-zacc[1][j]);  // zf
        const float e2 = __builtin_amdgcn_exp2f(-zacc[0][j]);  // zi
        const float e3 = __builtin_amdgcn_exp2f(zacc[2][j]);   // zg
        float cn = cpj * __builtin_amdgcn_rcpf(1.f + e1) +
                   (e3 - 1.f) * __builtin_amdgcn_rcpf((1.f + e2) * (1.f + e3));
        const float e4 = __builtin_amdgcn_exp2f(-zacc[3][j]);  // zo
        const float e5 = __builtin_amdgcn_exp2f(2.f * L2E * cn);
        float hn = (e5 - 1.f) * __builtin_amdgcn_rcpf((1.f + e4) * (1.f + e5));
        hn = ok ? hn : 0.f;
        cn = ok ? cn : 0.f;
        hcur[j] = hn;
        cnew[j] = cn;
        if (ok) out[oidx[j]] = hn;
      }
      const float up_h = bfbits2f((unsigned short)(pku >> 16));
      const float up_hp = bfbits2f((unsigned short)(pku & 0xffff));

      // ---- producer presum pass: P(d) rows + csj for step d+1 ----
#pragma unroll
      for (int j = 0; j < 4; ++j) {
        const float hup = j ? hcur[j - 1] : (hi16 ? up_h : gh1);
        const float hulp = j ? hnprev[j - 1] : (hi16 ? up_hp : gh2);
        const float sPj =
            ((cbase + 1 == j) || (R0 == 0 && hi16 == 0 && j == 0))
                ? 1.f : (1.f / 3.f);
        *(unsigned short*)(Pc + o_pw[j]) =
            f2bfbits(sPj * (hup + hcur[j] + hulp));
        const float cun = j ? cnew[j - 1] : (hi16 ? up_c : gc1);
        csj[j] = cun + cnew[j] + puv[j];
        puv[j] = cun;
      }
#pragma unroll
      for (int j = 0; j < 4; ++j) {
        hnprev[j] = hcur[j];
        oidx[j] += oStep;
      }
      ++cbase;

      // ---- tail: prefetch accA(d+1) from zbuf (written at step d-1) ----
      const float* zb = &zbuf[(d + 1) & 1][0] + (wq * 64 + L) * 4;
#pragma unroll
      for (int t = 0; t < 4; ++t) zacc[t] = *(const f32x4*)(zb + t * 1024);
    } else {
      // ---- helpers: poll ISSUE -> publish(w4) -> accx -> stage -> poll
      //      RESOLVE -> prog. Waves 4/5 alternate the poll by step parity.
      const bool meAct = (ch > 0) && (wq == ((d - R0) & 1));
      const int q = d + 3;
      const bool qLive = meAct && (q <= R0 + 126);
      const u64* qs = ring + ((linkDn * RDEPTH + (q & (RDEPTH - 1))) << 6) + L;
      u64 qv = 0;
      if (qLive)
        qv = __hip_atomic_load(qs, __ATOMIC_RELAXED, __HIP_MEMORY_SCOPE_AGENT);

      if (wq == 0 && ch < NCH - 1) {  // publish tag d-1 from pubbuf
        const int pd = d - 1;
        if (pd >= R0 + 15) {
          if (pd >= R0 + 15 + RDEPTH && gateSeen < pd - RDEPTH) {
            int spin = 0;
            do {
              gateSeen = __hip_atomic_load(&prog[linkUp * 16], __ATOMIC_RELAXED,
                                           __HIP_MEMORY_SCOPE_AGENT);
              if (gateSeen < pd - RDEPTH) __builtin_amdgcn_s_sleep(1);
            } while (gateSeen < pd - RDEPTH && ++spin < (1 << 22));
          }
          u64 v = pubbuf[(d - 1) & 1][L];
          u64* dst = ring + ((linkUp * RDEPTH + (pd & (RDEPTH - 1))) << 6) + L;
          __hip_atomic_store(dst, v, __ATOMIC_RELAXED,
                             __HIP_MEMORY_SCOPE_AGENT);
        }
      }
      accx(xA, (d + 2) & 1);
      stx(xB);  // x(d+3)
      ldg();    // px = x(d+4)
      if (qLive) {
        int spin = 0;
        while ((unsigned short)(qv >> 48) != (unsigned short)q &&
               spin < (1 << 22)) {
          ++spin;
          __builtin_amdgcn_s_sleep(1);
          qv = __hip_atomic_load(qs, __ATOMIC_RELAXED,
                                 __HIP_MEMORY_SCOPE_AGENT);
        }
        *(unsigned short*)(gbh + (q & 7) * 128 + L * 2) =
            (unsigned short)(qv >> 32);
        gbc[(q & 7) * 64 + L] = __uint_as_float((unsigned)qv);
      }
      if (meAct && L == 0)
        __hip_atomic_store(&prog[linkDn * 16], min(d + 3, R0 + 126),
                           __ATOMIC_RELAXED, __HIP_MEMORY_SCOPE_AGENT);
    }

    // rotate buffers (uniform, cheap pointer swaps)
    {
      unsigned char* t0 = xA; xA = xB; xB = xC; xC = t0;
      unsigned char* t1 = Pc; Pc = Pp; Pp = t1;
    }
    barrier_lds();  // single barrier: all LDS writes -> next step's reads
  }

  // final publish: tag D1 (written to pubbuf at step D1, barrier'd above)
  if (!isComp && wq == 0 && ch < NCH - 1) {
    const int pd = D1;
    if (pd >= R0 + 15 + RDEPTH && gateSeen < pd - RDEPTH) {
      int spin = 0;
      do {
        gateSeen = __hip_atomic_load(&prog[linkUp * 16], __ATOMIC_RELAXED,
                                     __HIP_MEMORY_SCOPE_AGENT);
        if (gateSeen < pd - RDEPTH) __builtin_amdgcn_s_sleep(1);
      } while (gateSeen < pd - RDEPTH && ++spin < (1 << 22));
    }
    u64 v = pubbuf[D1 & 1][L];
    u64* dst = ring + ((linkUp * RDEPTH + (pd & (RDEPTH - 1))) << 6) + L;
    __hip_atomic_store(dst, v, __ATOMIC_RELAXED, __HIP_MEMORY_SCOPE_AGENT);
  }
}

extern "C" void kernel_launch(void* const* d_in, const int* in_sizes, int n_in,
                              void* d_out, int out_size, void* d_ws, size_t ws_size,
                              hipStream_t stream) {
  const float* x = (const float*)d_in[0];
  const float* Wk = (const float*)d_in[1];
  const float* Wr = (const float*)d_in[2];
  const float* b = (const float*)d_in[3];
  float* out = (float*)d_out;
  // reset ring tags + progress flags every launch (graph-replay determinism)
  hipMemsetAsync(d_ws, 0, PROG_OFF + NLINK * 16 * sizeof(int), stream);
  hipLaunchKernelGGL(mdrnn_kernel, dim3(128), dim3(512), 0, stream, x, Wk, Wr,
                     b, out, (char*)d_ws);
}

// Round 6
// 234.910 us; speedup vs baseline: 1.3561x; 1.1099x over previous
//
#include <hip/hip_runtime.h>

typedef __bf16 bf16x8 __attribute__((ext_vector_type(8)));
typedef __bf16 bf16x4 __attribute__((ext_vector_type(4)));
typedef float f32x4 __attribute__((ext_vector_type(4)));
typedef unsigned long long u64;

#define NCH 8            // row-chunks per recurrence
#define CELLS 16         // rows per chunk
#define NG 256           // 4 gates * 64 units
#define L2E 1.44269504089f
#define RDEPTH 16                       // ring depth (tag mod 16)
#define NLINK (16 * 7)                  // (g, producer ch 0..6)
#define RING_U64 (NLINK * RDEPTH * 64)  // 896 KiB
#define PROG_OFF (RING_U64 * 8)         // byte offset of progress flags

__device__ __forceinline__ unsigned short f2bfbits(float f) {
  __bf16 b = (__bf16)f;
  return __builtin_bit_cast(unsigned short, b);
}
__device__ __forceinline__ float bfbits2f(unsigned short s) {
  return (float)__builtin_bit_cast(__bf16, s);
}
// LDS-only barrier: vmcnt stays in flight (out stores, x prefetch, ring ops)
__device__ __forceinline__ void barrier_lds() {
  asm volatile("s_waitcnt lgkmcnt(0)" ::: "memory");
  __builtin_amdgcn_s_barrier();
}
// 16B-granule XOR swizzle for 128B bf16 rows (row 0 identity -> linear).
__device__ __forceinline__ int hix(int row, int byteoff) {
  return row * 128 + (byteoff ^ ((row & 7) << 4));
}

// ROW-partitioned 2D-LSTM pipeline; WAVE-SPECIALIZED single-barrier step.
// Timing model (verified vs MfmaUtil): total = tau * p; tau = 255 + 7*eps
// (255 = 143 steps/chunk + 7 hops * 16-row geometric offset = algorithmic
// critical path), p ~= 2400 cyc. This round minimizes eps (compute-direct
// publish, gate pre-validated by helper wave 6) and trims p (single-rcp
// cell update, epilogue reorder).
// Block = (chunk ch, recurrence g), 512 thr = 8 waves (2/SIMD):
//   waves 0-3 (compute): {2x ds_read_b128 of pre-summed A-rows (P) + guard
//     reads, 16 h@Wr MFMA chained from C=accA(prefetched), LSTM epilogue
//     (j=3 first -> DIRECT ring publish + early shuffles), presum pass,
//     out stores, zacc prefetch}. Publish is pack+store only — the ring-
//     wrap gate for tag d was validated by wave 6 during step d-1 (barrier
//     orders it).
//   waves 4-7 (helper): accA(d+2)=x@Wk+b (8 MFMA) -> zbuf dbuf; stage
//     x(d+3)->xt tri-buf, prefetch x(d+4).
//     waves 4/5 alternate by parity: resolve ring tag d+3 (issue-early /
//       resolve-late), write gbh/gbc, update prog.
//     wave 6: pre-validates ring-wrap gate for tag d+1 (prog load issued
//       early, checked late; spins only if downstream lags >1 period).
__global__ __launch_bounds__(512, 1) void mdrnn_kernel(
    const float* __restrict__ x, const float* __restrict__ Wk,
    const float* __restrict__ Wr, const float* __restrict__ bias,
    float* __restrict__ out, char* __restrict__ ws) {
  __shared__ __align__(16) unsigned char xt[3][CELLS * 128];    // 6 KiB
  __shared__ __align__(16) unsigned char Pbuf[2][CELLS * 128];  // 4 KiB
  __shared__ __align__(16) unsigned char gbh[8 * 128];          // 1 KiB
  __shared__ __align__(16) float gbc[8 * 64];                   // 2 KiB
  __shared__ __align__(16) float zbuf[2][4096];                 // 32 KiB

  u64* __restrict__ ring = (u64*)ws;
  int* __restrict__ prog = (int*)(ws + PROG_OFF);  // 16-int (64B) stride

  const int tid = threadIdx.x;
  const bool isComp = (tid < 256);
  const int L = tid & 63;
  const int lo16 = L & 15;
  const int hi16 = L >> 4;
  const int wq = (tid >> 6) & 3;     // wave id within compute/helper group
  const int u = wq * 16 + lo16;      // unit-group index (both roles)
  const int hm0 = (tid >> 4) & 15;   // helper: staged row
  const int hq16 = tid & 15;         // helper: channel quad

  const int ch = blockIdx.x >> 4;   // bx%8 == g%8 -> chain on one XCD
  const int g = blockIdx.x & 15;
  const int f = g >> 2;
  const int bb = g & 3;
  const int fh = (f >> 1) & 1;
  const int fw = f & 1;
  const int R0 = ch * CELLS;
  const int D1 = R0 + 142;
  const int linkDn = g * 7 + ch - 1;
  const int linkUp = g * 7 + ch;

  for (int i = tid; i < 3 * CELLS * 32; i += 512) ((int*)xt)[i] = 0;
  for (int i = tid; i < 2 * CELLS * 32; i += 512) ((int*)Pbuf)[i] = 0;
  for (int i = tid; i < 8 * 32; i += 512) ((int*)gbh)[i] = 0;
  for (int i = tid; i < 8 * 64; i += 512) gbc[i] = 0.f;

  // ---- per-role constants ----
  float bsc[4] = {0.f, 0.f, 0.f, 0.f};
  bf16x8 wkh[4][2], wrh[4][2], wrl[4][2];
  int oidx[4];
  int oStep = 0, cbase = 0;
  int o_ph0 = 0, o_ph1 = 0;
  int o_pw[4] = {0, 0, 0, 0};
  if (isComp) {
    const float* Wrf = Wr + f * (64 * NG);
#pragma unroll
    for (int t = 0; t < 4; ++t) {
      const float st = (t == 2) ? (2.f * L2E) : L2E;
#pragma unroll
      for (int kt = 0; kt < 2; ++kt)
#pragma unroll
        for (int jj = 0; jj < 8; ++jj) {
          int k = kt * 32 + hi16 * 8 + jj;
          float vr = Wrf[k * NG + t * 64 + u] * st;
          __bf16 vh = (__bf16)vr;
          wrh[t][kt][jj] = vh;
          wrl[t][kt][jj] = (__bf16)(vr - (float)vh);
        }
    }
    const int ccStep = fw ? -1 : 1;
#pragma unroll
    for (int j = 0; j < 4; ++j) {
      int ro = R0 + hi16 * 4 + j;
      int rr = fh ? 127 - ro : ro;
      int c0 = R0 - ro;
      oidx[j] = ((bb * 128 + rr) * 128 + (fw ? 127 - c0 : c0)) * NG + f * 64 + u;
      o_pw[j] = hix(hi16 * 4 + j, u * 2);
    }
    oStep = ccStep * NG;
    cbase = -hi16 * 4;
    o_ph0 = hix(lo16, hi16 * 16);       // presummed A-row lo16, k 0..31
    o_ph1 = hix(lo16, 64 + hi16 * 16);  // k 32..63
  } else {
    const float* Wkf = Wk + f * (64 * NG);
#pragma unroll
    for (int t = 0; t < 4; ++t) {
      const float st = (t == 2) ? (2.f * L2E) : L2E;
      bsc[t] = bias[f * NG + t * 64 + u] * st;
#pragma unroll
      for (int kt = 0; kt < 2; ++kt)
#pragma unroll
        for (int jj = 0; jj < 8; ++jj) {
          int k = kt * 32 + hi16 * 8 + jj;
          wkh[t][kt][jj] = (__bf16)(Wkf[k * NG + t * 64 + u] * st);
        }
    }
  }
  const int o_ax0 = hix(lo16, hi16 * 16);
  const int o_ax1 = hix(lo16, 64 + hi16 * 16);

  // ---- helper-wave x addressing ----
  const int ccStepH = fw ? -1 : 1;
  const int rx = R0 + hm0;
  const int rrx = fh ? 127 - rx : rx;
  int cx = R0 - rx;
  int xidx = ((bb * 128 + rrx) * 128 + (fw ? 127 - cx : cx)) * 64 + hq16 * 4;
  const int xStep = ccStepH * 64;
  float4 px;
  bool pxv = false;
  auto ldg = [&]() {
    pxv = ((unsigned)cx <= 127u);
    px = make_float4(0.f, 0.f, 0.f, 0.f);
    if (pxv) px = *(const float4*)(x + xidx);
    xidx += xStep;
    ++cx;
  };
  auto stx = [&](unsigned char* buf) {
    if (pxv) {
      bf16x4 pk;
      pk[0] = (__bf16)px.x; pk[1] = (__bf16)px.y;
      pk[2] = (__bf16)px.z; pk[3] = (__bf16)px.w;
      *(bf16x4*)(buf + hix(hm0, hq16 * 8)) = pk;
    }
  };
  // helper: accA(tile) = x@Wk + b -> zbuf[bi] (conflict-free b128 lanes)
  auto accx = [&](const unsigned char* xp, int bi) {
    bf16x8 a0 = *(const bf16x8*)(xp + o_ax0);
    bf16x8 a1 = *(const bf16x8*)(xp + o_ax1);
    float* zw = &zbuf[bi][0] + (wq * 64 + L) * 4;
#pragma unroll
    for (int t = 0; t < 4; ++t) {
      f32x4 az = (f32x4){bsc[t], bsc[t], bsc[t], bsc[t]};
      az = __builtin_amdgcn_mfma_f32_16x16x32_bf16(a0, wkh[t][0], az, 0, 0, 0);
      az = __builtin_amdgcn_mfma_f32_16x16x32_bf16(a1, wkh[t][1], az, 0, 0, 0);
      *(f32x4*)(zw + t * 1024) = az;
    }
  };

  __syncthreads();  // S0: zero-init visible

  if (!isComp) {
    ldg();                       // px = x(R0)
    stx(&xt[R0 % 3][0]);
    ldg();                       // px = x(R0+1)
  }
  __syncthreads();  // S1: xt(R0) visible

  if (!isComp) {
    stx(&xt[(R0 + 1) % 3][0]);   // stage x(R0+1)
    ldg();                       // px = x(R0+2)
    accx(&xt[R0 % 3][0], R0 & 1);
    // pre-loop poll (wave 4): tags R0-1..R0+2; P-init row 0 from tag R0-1
    if (wq == 0 && ch > 0) {
#pragma unroll
      for (int k = 0; k < 4; ++k) {
        const int q = R0 - 1 + k;
        u64* src = ring + ((linkDn * RDEPTH + (q & (RDEPTH - 1))) << 6) + L;
        u64 v;
        int spin = 0;
        for (;;) {
          v = __hip_atomic_load(src, __ATOMIC_RELAXED, __HIP_MEMORY_SCOPE_AGENT);
          if ((unsigned short)(v >> 48) == (unsigned short)q ||
              spin >= (1 << 22))
            break;
          ++spin;
          __builtin_amdgcn_s_sleep(2);
        }
        *(unsigned short*)(gbh + (q & 7) * 128 + L * 2) =
            (unsigned short)(v >> 32);
        gbc[(q & 7) * 64 + L] = __uint_as_float((unsigned)v);
        if (k == 0)  // P(R0-1)[row0] = guard h (scale 1; rest stays zero)
          *(unsigned short*)(&Pbuf[(R0 + 1) & 1][0] + L * 2) =
              (unsigned short)(v >> 32);
      }
      if (L == 0)
        __hip_atomic_store(&prog[linkDn * 16], R0 + 2, __ATOMIC_RELAXED,
                           __HIP_MEMORY_SCOPE_AGENT);
    }
  }
  __syncthreads();  // S2: xt(R0+1), zbuf(R0), gbh/gbc, P-init visible

  // ---- compute-wave carried state ----
  f32x4 zacc[4];
  float hnprev[4];  // this lane's h(d-1)[rows lm] (masked)
  float csj[4];     // presummed c for the CURRENT step
  float puv[4];     // carried c_ul = prev step's c_up
  int gateSeen = 0;  // helper wave 6 only
  if (isComp) {
    const float* zb = &zbuf[R0 & 1][0] + (wq * 64 + L) * 4;
#pragma unroll
    for (int t = 0; t < 4; ++t) zacc[t] = *(const f32x4*)(zb + t * 1024);
    const float cu0 = gbc[((R0 - 1) & 7) * 64 + u];  // zero for ch==0
#pragma unroll
    for (int j = 0; j < 4; ++j) {
      const float ci = (hi16 == 0 && j == 0) ? cu0 : 0.f;
      csj[j] = ci;
      puv[j] = ci;
      hnprev[j] = 0.f;
    }
    __builtin_amdgcn_s_setprio(1);  // compute waves favored over helpers
  } else {
    accx(&xt[(R0 + 1) % 3][0], (R0 + 1) & 1);
    stx(&xt[(R0 + 2) % 3][0]);   // stage x(R0+2)
    ldg();                       // px = x(R0+3)
  }
  __syncthreads();  // S3: zbuf(R0+1), xt(R0+2) visible

  // rotating pointers (uniform)
  unsigned char* Pc = &Pbuf[R0 & 1][0];        // written this step
  unsigned char* Pp = &Pbuf[(R0 + 1) & 1][0];  // read this step
  unsigned char* xA = &xt[(R0 + 2) % 3][0];    // accx read (x(d+2))
  unsigned char* xB = &xt[R0 % 3][0];          // stx write (x(d+3))
  unsigned char* xC = &xt[(R0 + 1) % 3][0];

  for (int d = R0; d <= D1; ++d) {
    if (isComp) {
      // ---- post-barrier critical region: 2 loads -> 16 MFMA ----
      bf16x8 pa0 = *(const bf16x8*)(Pp + o_ph0);
      bf16x8 pa1 = *(const bf16x8*)(Pp + o_ph1);
      // guard reads hoisted pre-MFMA (latency hides under MFMAs); row-0
      // swizzle of gbh rows is identity (linear). Stale slots only feed
      // masked-out rows.
      const float gh1 = bfbits2f(*(const unsigned short*)(gbh + (d & 7) * 128 + u * 2));
      const float gh2 = bfbits2f(*(const unsigned short*)(gbh + ((d - 1) & 7) * 128 + u * 2));
      const float gc1 = gbc[(d & 7) * 64 + u];
#pragma unroll
      for (int t = 0; t < 4; ++t)
        zacc[t] = __builtin_amdgcn_mfma_f32_16x16x32_bf16(pa0, wrh[t][0], zacc[t], 0, 0, 0);
#pragma unroll
      for (int t = 0; t < 4; ++t)
        zacc[t] = __builtin_amdgcn_mfma_f32_16x16x32_bf16(pa1, wrh[t][1], zacc[t], 0, 0, 0);
#pragma unroll
      for (int t = 0; t < 4; ++t)
        zacc[t] = __builtin_amdgcn_mfma_f32_16x16x32_bf16(pa0, wrl[t][0], zacc[t], 0, 0, 0);
#pragma unroll
      for (int t = 0; t < 4; ++t)
        zacc[t] = __builtin_amdgcn_mfma_f32_16x16x32_bf16(pa1, wrl[t][1], zacc[t], 0, 0, 0);

      const bool pubW = (ch < NCH - 1) && (d >= R0 + 15);

      // ---- epilogue: j=3 first (feeds publish + cross-row shuffles) ----
      float hcur[4], cnew[4];
      {
        const int cj = cbase - 3;
        const bool ok = ((unsigned)cj <= 127u);
        const float inv = (cj == 0) ? 1.f : (1.f / 3.f);  // lm>=3 -> r>0
        const float cpj = csj[3] * inv;
        const float e1 = __builtin_amdgcn_exp2f(-zacc[1][3]);  // zf
        const float e2 = __builtin_amdgcn_exp2f(-zacc[0][3]);  // zi
        const float e3 = __builtin_amdgcn_exp2f(zacc[2][3]);   // zg
        const float A = 1.f + e1, Bv = 1.f + e2, Cv = 1.f + e3;
        const float BC = Bv * Cv;
        float cn = (cpj * BC + (e3 - 1.f) * A) *
                   __builtin_amdgcn_rcpf(A * BC);
        const float e4 = __builtin_amdgcn_exp2f(-zacc[3][3]);  // zo
        const float e5 = __builtin_amdgcn_exp2f(2.f * L2E * cn);
        float hn = (e5 - 1.f) * __builtin_amdgcn_rcpf((1.f + e4) * (1.f + e5));
        if (pubW && hi16 == 3) {  // DIRECT publish: pack + store, no gate
          u64 v = ((u64)(unsigned short)d << 48) | ((u64)f2bfbits(hn) << 32) |
                  (u64)__float_as_uint(cn);
          u64* dst = ring + ((linkUp * RDEPTH + (d & (RDEPTH - 1))) << 6) + u;
          __hip_atomic_store(dst, v, __ATOMIC_RELAXED,
                             __HIP_MEMORY_SCOPE_AGENT);
        }
        hcur[3] = ok ? hn : 0.f;
        cnew[3] = ok ? cn : 0.f;
      }
      // issue cross-row shuffles early (hide ds_bpermute under j=2..0)
      const unsigned pk =
          ((unsigned)f2bfbits(hcur[3]) << 16) | f2bfbits(hnprev[3]);
      const unsigned pku = __shfl((int)pk, (L - 16) & 63);
      const float up_c = __shfl(cnew[3], (L - 16) & 63);
#pragma unroll
      for (int jj = 0; jj < 3; ++jj) {
        const int j = 2 - jj;
        const int cj = cbase - j;
        const bool ok = ((unsigned)cj <= 127u);
        const float inv =
            (cj == 0 || (j == 0 && R0 == 0 && hi16 == 0)) ? 1.f : (1.f / 3.f);
        const float cpj = csj[j] * inv;
        const float e1 = __builtin_amdgcn_exp2f(-zacc[1][j]);  // zf
        const float e2 = __builtin_amdgcn_exp2f(-zacc[0][j]);  // zi
        const float e3 = __builtin_amdgcn_exp2f(zacc[2][j]);   // zg
        const float A = 1.f + e1, Bv = 1.f + e2, Cv = 1.f + e3;
        const float BC = Bv * Cv;
        float cn = (cpj * BC + (e3 - 1.f) * A) *
                   __builtin_amdgcn_rcpf(A * BC);
        const float e4 = __builtin_amdgcn_exp2f(-zacc[3][j]);  // zo
        const float e5 = __builtin_amdgcn_exp2f(2.f * L2E * cn);
        float hn = (e5 - 1.f) * __builtin_amdgcn_rcpf((1.f + e4) * (1.f + e5));
        hcur[j] = ok ? hn : 0.f;
        cnew[j] = ok ? cn : 0.f;
      }
      const float up_h = bfbits2f((unsigned short)(pku >> 16));
      const float up_hp = bfbits2f((unsigned short)(pku & 0xffff));

      // ---- producer presum pass: P(d) rows + csj for step d+1 ----
#pragma unroll
      for (int j = 0; j < 4; ++j) {
        const float hup = j ? hcur[j - 1] : (hi16 ? up_h : gh1);
        const float hulp = j ? hnprev[j - 1] : (hi16 ? up_hp : gh2);
        const float sPj =
            ((cbase + 1 == j) || (R0 == 0 && hi16 == 0 && j == 0))
                ? 1.f : (1.f / 3.f);
        *(unsigned short*)(Pc + o_pw[j]) =
            f2bfbits(sPj * (hup + hcur[j] + hulp));
        const float cun = j ? cnew[j - 1] : (hi16 ? up_c : gc1);
        csj[j] = cun + cnew[j] + puv[j];
        puv[j] = cun;
      }
      // ---- out stores after P-write (pure sinks, off the lgkm path) ----
#pragma unroll
      for (int j = 0; j < 4; ++j) {
        if ((unsigned)(cbase - j) <= 127u) out[oidx[j]] = hcur[j];
        hnprev[j] = hcur[j];
        oidx[j] += oStep;
      }
      ++cbase;

      // ---- tail: prefetch accA(d+1) from zbuf (written at step d-1) ----
      const float* zb = &zbuf[(d + 1) & 1][0] + (wq * 64 + L) * 4;
#pragma unroll
      for (int t = 0; t < 4; ++t) zacc[t] = *(const f32x4*)(zb + t * 1024);
    } else {
      // ---- helpers: poll/gate ISSUE -> accx -> stage -> RESOLVE ----
      const bool meAct = (ch > 0) && (wq == ((d - R0) & 1));
      const int q = d + 3;
      const bool qLive = meAct && (q <= R0 + 126);
      const u64* qs = ring + ((linkDn * RDEPTH + (q & (RDEPTH - 1))) << 6) + L;
      u64 qv = 0;
      if (qLive)
        qv = __hip_atomic_load(qs, __ATOMIC_RELAXED, __HIP_MEMORY_SCOPE_AGENT);
      // wave 6: pre-validate ring-wrap gate for tag d+1 (compute publishes
      // it next step; barrier orders this pass before that publish).
      const int nt = d + 1;
      const bool gatev = (wq == 2) && (ch < NCH - 1) && (nt <= D1) &&
                         (nt >= R0 + 15 + RDEPTH);
      int progNow = gateSeen;
      if (gatev && gateSeen < nt - RDEPTH)
        progNow = __hip_atomic_load(&prog[linkUp * 16], __ATOMIC_RELAXED,
                                    __HIP_MEMORY_SCOPE_AGENT);

      accx(xA, (d + 2) & 1);
      stx(xB);  // x(d+3)
      ldg();    // px = x(d+4)

      if (qLive) {
        int spin = 0;
        while ((unsigned short)(qv >> 48) != (unsigned short)q &&
               spin < (1 << 22)) {
          ++spin;
          __builtin_amdgcn_s_sleep(1);
          qv = __hip_atomic_load(qs, __ATOMIC_RELAXED,
                                 __HIP_MEMORY_SCOPE_AGENT);
        }
        *(unsigned short*)(gbh + (q & 7) * 128 + L * 2) =
            (unsigned short)(qv >> 32);
        gbc[(q & 7) * 64 + L] = __uint_as_float((unsigned)qv);
      }
      if (meAct && L == 0)
        __hip_atomic_store(&prog[linkDn * 16], min(d + 3, R0 + 126),
                           __ATOMIC_RELAXED, __HIP_MEMORY_SCOPE_AGENT);
      if (gatev) {
        if (progNow > gateSeen) gateSeen = progNow;
        int spin = 0;
        while (gateSeen < nt - RDEPTH && spin < (1 << 22)) {
          ++spin;
          __builtin_amdgcn_s_sleep(1);
          gateSeen = __hip_atomic_load(&prog[linkUp * 16], __ATOMIC_RELAXED,
                                       __HIP_MEMORY_SCOPE_AGENT);
        }
      }
    }

    // rotate buffers (uniform, cheap pointer swaps)
    {
      unsigned char* t0 = xA; xA = xB; xB = xC; xC = t0;
      unsigned char* t1 = Pc; Pc = Pp; Pp = t1;
    }
    barrier_lds();  // single barrier: all LDS writes -> next step's reads
  }
}

extern "C" void kernel_launch(void* const* d_in, const int* in_sizes, int n_in,
                              void* d_out, int out_size, void* d_ws, size_t ws_size,
                              hipStream_t stream) {
  const float* x = (const float*)d_in[0];
  const float* Wk = (const float*)d_in[1];
  const float* Wr = (const float*)d_in[2];
  const float* b = (const float*)d_in[3];
  float* out = (float*)d_out;
  // reset ring tags + progress flags every launch (graph-replay determinism)
  hipMemsetAsync(d_ws, 0, PROG_OFF + NLINK * 16 * sizeof(int), stream);
  hipLaunchKernelGGL(mdrnn_kernel, dim3(128), dim3(512), 0, stream, x, Wk, Wr,
                     b, out, (char*)d_ws);
}

// Round 7
// 233.351 us; speedup vs baseline: 1.3652x; 1.0067x over previous
//
#include <hip/hip_runtime.h>

typedef __bf16 bf16x8 __attribute__((ext_vector_type(8)));
typedef __bf16 bf16x4 __attribute__((ext_vector_type(4)));
typedef float f32x4 __attribute__((ext_vector_type(4)));
typedef unsigned long long u64;

#define NCH 8            // row-chunks per recurrence
#define CELLS 16         // rows per chunk
#define NG 256           // 4 gates * 64 units
#define L2E 1.44269504089f
#define RDEPTH 16                       // ring depth (tag mod 16)
#define NLINK (16 * 7)                  // (g, producer ch 0..6)
#define RING_U64 (NLINK * RDEPTH * 64)  // 896 KiB
#define PROG_OFF (RING_U64 * 8)         // byte offset of progress flags

__device__ __forceinline__ unsigned short f2bfbits(float f) {
  __bf16 b = (__bf16)f;
  return __builtin_bit_cast(unsigned short, b);
}
__device__ __forceinline__ float bfbits2f(unsigned short s) {
  return (float)__builtin_bit_cast(__bf16, s);
}
// LDS-only barrier: vmcnt stays in flight (out stores, x prefetch, ring ops)
__device__ __forceinline__ void barrier_lds() {
  asm volatile("s_waitcnt lgkmcnt(0)" ::: "memory");
  __builtin_amdgcn_s_barrier();
}
// 16B-granule XOR swizzle for 128B bf16 rows (row 0 identity -> linear).
__device__ __forceinline__ int hix(int row, int byteoff) {
  return row * 128 + (byteoff ^ ((row & 7) << 4));
}

// ROW-partitioned 2D-LSTM pipeline; WAVE-SPECIALIZED single-barrier step.
// Timing model: total = tau * p; tau = 254 + 7*s (s = per-hop skew), p =
// per-step period (~2040 cyc at R6). The poll lookahead IS the skew: the
// resolve at step d blocks on the polled tag's publication. This round:
// lookahead 3 -> 1 (tau 276 -> ~262) and zacc-prefetch hoisted above the
// epilogue (p -~100cy; ds_read latency hides under transcendentals).
// Block = (chunk ch, recurrence g), 512 thr = 8 waves (2/SIMD):
//   waves 0-3 (compute): {2x ds_read_b128 of pre-summed A-rows (P) + guard
//     reads, 16 h@Wr MFMA chained from C=accA(prefetched), znx prefetch,
//     LSTM epilogue (j=3 first -> DIRECT ring publish + early shuffles),
//     presum pass, out stores, zacc <- znx}. Publish is pack+store only —
//     the ring-wrap gate for tag d was validated by wave 6 at step d-1.
//   waves 4-7 (helper): accA(d+2)=x@Wk+b (8 MFMA) -> zbuf dbuf; stage
//     x(d+3)->xt tri-buf, prefetch x(d+4).
//     waves 4/5 alternate by parity: resolve ring tag d+1 (issue-early /
//       resolve-late), write gbh/gbc, update prog.
//     wave 6: pre-validates ring-wrap gate for tag d+1 (prog load issued
//       early, checked late; spins only if downstream lags > RDEPTH-1).
__global__ __launch_bounds__(512, 1) void mdrnn_kernel(
    const float* __restrict__ x, const float* __restrict__ Wk,
    const float* __restrict__ Wr, const float* __restrict__ bias,
    float* __restrict__ out, char* __restrict__ ws) {
  __shared__ __align__(16) unsigned char xt[3][CELLS * 128];    // 6 KiB
  __shared__ __align__(16) unsigned char Pbuf[2][CELLS * 128];  // 4 KiB
  __shared__ __align__(16) unsigned char gbh[8 * 128];          // 1 KiB
  __shared__ __align__(16) float gbc[8 * 64];                   // 2 KiB
  __shared__ __align__(16) float zbuf[2][4096];                 // 32 KiB

  u64* __restrict__ ring = (u64*)ws;
  int* __restrict__ prog = (int*)(ws + PROG_OFF);  // 16-int (64B) stride

  const int tid = threadIdx.x;
  const bool isComp = (tid < 256);
  const int L = tid & 63;
  const int lo16 = L & 15;
  const int hi16 = L >> 4;
  const int wq = (tid >> 6) & 3;     // wave id within compute/helper group
  const int u = wq * 16 + lo16;      // unit-group index (both roles)
  const int hm0 = (tid >> 4) & 15;   // helper: staged row
  const int hq16 = tid & 15;         // helper: channel quad

  const int ch = blockIdx.x >> 4;   // bx%8 == g%8 -> chain on one XCD
  const int g = blockIdx.x & 15;
  const int f = g >> 2;
  const int bb = g & 3;
  const int fh = (f >> 1) & 1;
  const int fw = f & 1;
  const int R0 = ch * CELLS;
  const int D1 = R0 + 142;
  const int linkDn = g * 7 + ch - 1;
  const int linkUp = g * 7 + ch;

  for (int i = tid; i < 3 * CELLS * 32; i += 512) ((int*)xt)[i] = 0;
  for (int i = tid; i < 2 * CELLS * 32; i += 512) ((int*)Pbuf)[i] = 0;
  for (int i = tid; i < 8 * 32; i += 512) ((int*)gbh)[i] = 0;
  for (int i = tid; i < 8 * 64; i += 512) gbc[i] = 0.f;

  // ---- per-role constants ----
  float bsc[4] = {0.f, 0.f, 0.f, 0.f};
  bf16x8 wkh[4][2], wrh[4][2], wrl[4][2];
  int oidx[4];
  int oStep = 0, cbase = 0;
  int o_ph0 = 0, o_ph1 = 0;
  int o_pw[4] = {0, 0, 0, 0};
  if (isComp) {
    const float* Wrf = Wr + f * (64 * NG);
#pragma unroll
    for (int t = 0; t < 4; ++t) {
      const float st = (t == 2) ? (2.f * L2E) : L2E;
#pragma unroll
      for (int kt = 0; kt < 2; ++kt)
#pragma unroll
        for (int jj = 0; jj < 8; ++jj) {
          int k = kt * 32 + hi16 * 8 + jj;
          float vr = Wrf[k * NG + t * 64 + u] * st;
          __bf16 vh = (__bf16)vr;
          wrh[t][kt][jj] = vh;
          wrl[t][kt][jj] = (__bf16)(vr - (float)vh);
        }
    }
    const int ccStep = fw ? -1 : 1;
#pragma unroll
    for (int j = 0; j < 4; ++j) {
      int ro = R0 + hi16 * 4 + j;
      int rr = fh ? 127 - ro : ro;
      int c0 = R0 - ro;
      oidx[j] = ((bb * 128 + rr) * 128 + (fw ? 127 - c0 : c0)) * NG + f * 64 + u;
      o_pw[j] = hix(hi16 * 4 + j, u * 2);
    }
    oStep = ccStep * NG;
    cbase = -hi16 * 4;
    o_ph0 = hix(lo16, hi16 * 16);       // presummed A-row lo16, k 0..31
    o_ph1 = hix(lo16, 64 + hi16 * 16);  // k 32..63
  } else {
    const float* Wkf = Wk + f * (64 * NG);
#pragma unroll
    for (int t = 0; t < 4; ++t) {
      const float st = (t == 2) ? (2.f * L2E) : L2E;
      bsc[t] = bias[f * NG + t * 64 + u] * st;
#pragma unroll
      for (int kt = 0; kt < 2; ++kt)
#pragma unroll
        for (int jj = 0; jj < 8; ++jj) {
          int k = kt * 32 + hi16 * 8 + jj;
          wkh[t][kt][jj] = (__bf16)(Wkf[k * NG + t * 64 + u] * st);
        }
    }
  }
  const int o_ax0 = hix(lo16, hi16 * 16);
  const int o_ax1 = hix(lo16, 64 + hi16 * 16);

  // ---- helper-wave x addressing ----
  const int ccStepH = fw ? -1 : 1;
  const int rx = R0 + hm0;
  const int rrx = fh ? 127 - rx : rx;
  int cx = R0 - rx;
  int xidx = ((bb * 128 + rrx) * 128 + (fw ? 127 - cx : cx)) * 64 + hq16 * 4;
  const int xStep = ccStepH * 64;
  float4 px;
  bool pxv = false;
  auto ldg = [&]() {
    pxv = ((unsigned)cx <= 127u);
    px = make_float4(0.f, 0.f, 0.f, 0.f);
    if (pxv) px = *(const float4*)(x + xidx);
    xidx += xStep;
    ++cx;
  };
  auto stx = [&](unsigned char* buf) {
    if (pxv) {
      bf16x4 pk;
      pk[0] = (__bf16)px.x; pk[1] = (__bf16)px.y;
      pk[2] = (__bf16)px.z; pk[3] = (__bf16)px.w;
      *(bf16x4*)(buf + hix(hm0, hq16 * 8)) = pk;
    }
  };
  // helper: accA(tile) = x@Wk + b -> zbuf[bi] (conflict-free b128 lanes)
  auto accx = [&](const unsigned char* xp, int bi) {
    bf16x8 a0 = *(const bf16x8*)(xp + o_ax0);
    bf16x8 a1 = *(const bf16x8*)(xp + o_ax1);
    float* zw = &zbuf[bi][0] + (wq * 64 + L) * 4;
#pragma unroll
    for (int t = 0; t < 4; ++t) {
      f32x4 az = (f32x4){bsc[t], bsc[t], bsc[t], bsc[t]};
      az = __builtin_amdgcn_mfma_f32_16x16x32_bf16(a0, wkh[t][0], az, 0, 0, 0);
      az = __builtin_amdgcn_mfma_f32_16x16x32_bf16(a1, wkh[t][1], az, 0, 0, 0);
      *(f32x4*)(zw + t * 1024) = az;
    }
  };

  __syncthreads();  // S0: zero-init visible

  if (!isComp) {
    ldg();                       // px = x(R0)
    stx(&xt[R0 % 3][0]);
    ldg();                       // px = x(R0+1)
  }
  __syncthreads();  // S1: xt(R0) visible

  if (!isComp) {
    stx(&xt[(R0 + 1) % 3][0]);   // stage x(R0+1)
    ldg();                       // px = x(R0+2)
    accx(&xt[R0 % 3][0], R0 & 1);
    // pre-loop poll (wave 4): tags R0-1..R0+2; P-init row 0 from tag R0-1
    if (wq == 0 && ch > 0) {
#pragma unroll
      for (int k = 0; k < 4; ++k) {
        const int q = R0 - 1 + k;
        u64* src = ring + ((linkDn * RDEPTH + (q & (RDEPTH - 1))) << 6) + L;
        u64 v;
        int spin = 0;
        for (;;) {
          v = __hip_atomic_load(src, __ATOMIC_RELAXED, __HIP_MEMORY_SCOPE_AGENT);
          if ((unsigned short)(v >> 48) == (unsigned short)q ||
              spin >= (1 << 22))
            break;
          ++spin;
          __builtin_amdgcn_s_sleep(2);
        }
        *(unsigned short*)(gbh + (q & 7) * 128 + L * 2) =
            (unsigned short)(v >> 32);
        gbc[(q & 7) * 64 + L] = __uint_as_float((unsigned)v);
        if (k == 0)  // P(R0-1)[row0] = guard h (scale 1; rest stays zero)
          *(unsigned short*)(&Pbuf[(R0 + 1) & 1][0] + L * 2) =
              (unsigned short)(v >> 32);
      }
      if (L == 0)
        __hip_atomic_store(&prog[linkDn * 16], R0 + 2, __ATOMIC_RELAXED,
                           __HIP_MEMORY_SCOPE_AGENT);
    }
  }
  __syncthreads();  // S2: xt(R0+1), zbuf(R0), gbh/gbc, P-init visible

  // ---- compute-wave carried state ----
  f32x4 zacc[4];
  float hnprev[4];  // this lane's h(d-1)[rows lm] (masked)
  float csj[4];     // presummed c for the CURRENT step
  float puv[4];     // carried c_ul = prev step's c_up
  int gateSeen = 0;  // helper wave 6 only
  if (isComp) {
    const float* zb = &zbuf[R0 & 1][0] + (wq * 64 + L) * 4;
#pragma unroll
    for (int t = 0; t < 4; ++t) zacc[t] = *(const f32x4*)(zb + t * 1024);
    const float cu0 = gbc[((R0 - 1) & 7) * 64 + u];  // zero for ch==0
#pragma unroll
    for (int j = 0; j < 4; ++j) {
      const float ci = (hi16 == 0 && j == 0) ? cu0 : 0.f;
      csj[j] = ci;
      puv[j] = ci;
      hnprev[j] = 0.f;
    }
    __builtin_amdgcn_s_setprio(1);  // compute waves favored over helpers
  } else {
    accx(&xt[(R0 + 1) % 3][0], (R0 + 1) & 1);
    stx(&xt[(R0 + 2) % 3][0]);   // stage x(R0+2)
    ldg();                       // px = x(R0+3)
  }
  __syncthreads();  // S3: zbuf(R0+1), xt(R0+2) visible

  // rotating pointers (uniform)
  unsigned char* Pc = &Pbuf[R0 & 1][0];        // written this step
  unsigned char* Pp = &Pbuf[(R0 + 1) & 1][0];  // read this step
  unsigned char* xA = &xt[(R0 + 2) % 3][0];    // accx read (x(d+2))
  unsigned char* xB = &xt[R0 % 3][0];          // stx write (x(d+3))
  unsigned char* xC = &xt[(R0 + 1) % 3][0];

  for (int d = R0; d <= D1; ++d) {
    if (isComp) {
      // ---- post-barrier critical region: 2 loads -> 16 MFMA ----
      bf16x8 pa0 = *(const bf16x8*)(Pp + o_ph0);
      bf16x8 pa1 = *(const bf16x8*)(Pp + o_ph1);
      // guard reads hoisted pre-MFMA (latency hides under MFMAs); row-0
      // swizzle of gbh rows is identity (linear). Stale slots only feed
      // masked-out rows.
      const float gh1 = bfbits2f(*(const unsigned short*)(gbh + (d & 7) * 128 + u * 2));
      const float gh2 = bfbits2f(*(const unsigned short*)(gbh + ((d - 1) & 7) * 128 + u * 2));
      const float gc1 = gbc[(d & 7) * 64 + u];
#pragma unroll
      for (int t = 0; t < 4; ++t)
        zacc[t] = __builtin_amdgcn_mfma_f32_16x16x32_bf16(pa0, wrh[t][0], zacc[t], 0, 0, 0);
#pragma unroll
      for (int t = 0; t < 4; ++t)
        zacc[t] = __builtin_amdgcn_mfma_f32_16x16x32_bf16(pa1, wrh[t][1], zacc[t], 0, 0, 0);
#pragma unroll
      for (int t = 0; t < 4; ++t)
        zacc[t] = __builtin_amdgcn_mfma_f32_16x16x32_bf16(pa0, wrl[t][0], zacc[t], 0, 0, 0);
#pragma unroll
      for (int t = 0; t < 4; ++t)
        zacc[t] = __builtin_amdgcn_mfma_f32_16x16x32_bf16(pa1, wrl[t][1], zacc[t], 0, 0, 0);

      // ---- prefetch accA(d+1) EARLY (zbuf[(d+1)&1] stable all step d);
      //      ds_read latency hides under the epilogue transcendentals ----
      const float* zbn = &zbuf[(d + 1) & 1][0] + (wq * 64 + L) * 4;
      const f32x4 znx0 = *(const f32x4*)(zbn);
      const f32x4 znx1 = *(const f32x4*)(zbn + 1024);
      const f32x4 znx2 = *(const f32x4*)(zbn + 2048);
      const f32x4 znx3 = *(const f32x4*)(zbn + 3072);

      const bool pubW = (ch < NCH - 1) && (d >= R0 + 15);

      // ---- epilogue: j=3 first (feeds publish + cross-row shuffles) ----
      float hcur[4], cnew[4];
      {
        const int cj = cbase - 3;
        const bool ok = ((unsigned)cj <= 127u);
        const float inv = (cj == 0) ? 1.f : (1.f / 3.f);  // lm>=3 -> r>0
        const float cpj = csj[3] * inv;
        const float e1 = __builtin_amdgcn_exp2f(-zacc[1][3]);  // zf
        const float e2 = __builtin_amdgcn_exp2f(-zacc[0][3]);  // zi
        const float e3 = __builtin_amdgcn_exp2f(zacc[2][3]);   // zg
        const float A = 1.f + e1, Bv = 1.f + e2, Cv = 1.f + e3;
        const float BC = Bv * Cv;
        float cn = (cpj * BC + (e3 - 1.f) * A) *
                   __builtin_amdgcn_rcpf(A * BC);
        const float e4 = __builtin_amdgcn_exp2f(-zacc[3][3]);  // zo
        const float e5 = __builtin_amdgcn_exp2f(2.f * L2E * cn);
        float hn = (e5 - 1.f) * __builtin_amdgcn_rcpf((1.f + e4) * (1.f + e5));
        if (pubW && hi16 == 3) {  // DIRECT publish: pack + store, no gate
          u64 v = ((u64)(unsigned short)d << 48) | ((u64)f2bfbits(hn) << 32) |
                  (u64)__float_as_uint(cn);
          u64* dst = ring + ((linkUp * RDEPTH + (d & (RDEPTH - 1))) << 6) + u;
          __hip_atomic_store(dst, v, __ATOMIC_RELAXED,
                             __HIP_MEMORY_SCOPE_AGENT);
        }
        hcur[3] = ok ? hn : 0.f;
        cnew[3] = ok ? cn : 0.f;
      }
      // issue cross-row shuffles early (hide ds_bpermute under j=2..0)
      const unsigned pk =
          ((unsigned)f2bfbits(hcur[3]) << 16) | f2bfbits(hnprev[3]);
      const unsigned pku = __shfl((int)pk, (L - 16) & 63);
      const float up_c = __shfl(cnew[3], (L - 16) & 63);
#pragma unroll
      for (int jj = 0; jj < 3; ++jj) {
        const int j = 2 - jj;
        const int cj = cbase - j;
        const bool ok = ((unsigned)cj <= 127u);
        const float inv =
            (cj == 0 || (j == 0 && R0 == 0 && hi16 == 0)) ? 1.f : (1.f / 3.f);
        const float cpj = csj[j] * inv;
        const float e1 = __builtin_amdgcn_exp2f(-zacc[1][j]);  // zf
        const float e2 = __builtin_amdgcn_exp2f(-zacc[0][j]);  // zi
        const float e3 = __builtin_amdgcn_exp2f(zacc[2][j]);   // zg
        const float A = 1.f + e1, Bv = 1.f + e2, Cv = 1.f + e3;
        const float BC = Bv * Cv;
        float cn = (cpj * BC + (e3 - 1.f) * A) *
                   __builtin_amdgcn_rcpf(A * BC);
        const float e4 = __builtin_amdgcn_exp2f(-zacc[3][j]);  // zo
        const float e5 = __builtin_amdgcn_exp2f(2.f * L2E * cn);
        float hn = (e5 - 1.f) * __builtin_amdgcn_rcpf((1.f + e4) * (1.f + e5));
        hcur[j] = ok ? hn : 0.f;
        cnew[j] = ok ? cn : 0.f;
      }
      const float up_h = bfbits2f((unsigned short)(pku >> 16));
      const float up_hp = bfbits2f((unsigned short)(pku & 0xffff));

      // ---- producer presum pass: P(d) rows + csj for step d+1 ----
#pragma unroll
      for (int j = 0; j < 4; ++j) {
        const float hup = j ? hcur[j - 1] : (hi16 ? up_h : gh1);
        const float hulp = j ? hnprev[j - 1] : (hi16 ? up_hp : gh2);
        const float sPj =
            ((cbase + 1 == j) || (R0 == 0 && hi16 == 0 && j == 0))
                ? 1.f : (1.f / 3.f);
        *(unsigned short*)(Pc + o_pw[j]) =
            f2bfbits(sPj * (hup + hcur[j] + hulp));
        const float cun = j ? cnew[j - 1] : (hi16 ? up_c : gc1);
        csj[j] = cun + cnew[j] + puv[j];
        puv[j] = cun;
      }
      // ---- out stores after P-write (pure sinks, off the lgkm path) ----
#pragma unroll
      for (int j = 0; j < 4; ++j) {
        if ((unsigned)(cbase - j) <= 127u) out[oidx[j]] = hcur[j];
        hnprev[j] = hcur[j];
        oidx[j] += oStep;
      }
      ++cbase;

      // ---- tail: commit prefetched accA(d+1) ----
      zacc[0] = znx0; zacc[1] = znx1; zacc[2] = znx2; zacc[3] = znx3;
    } else {
      // ---- helpers: poll/gate ISSUE -> accx -> stage -> RESOLVE ----
      const bool meAct = (ch > 0) && (wq == ((d - R0) & 1));
      const int q = d + 1;  // lookahead 1 == per-hop skew 1
      const bool qLive = meAct && (q >= R0 + 3) && (q <= R0 + 126);
      const u64* qs = ring + ((linkDn * RDEPTH + (q & (RDEPTH - 1))) << 6) + L;
      u64 qv = 0;
      if (qLive)
        qv = __hip_atomic_load(qs, __ATOMIC_RELAXED, __HIP_MEMORY_SCOPE_AGENT);
      // wave 6: pre-validate ring-wrap gate for tag d+1 (compute publishes
      // it next step; barrier orders this pass before that publish).
      const int nt = d + 1;
      const bool gatev = (wq == 2) && (ch < NCH - 1) && (nt <= D1) &&
                         (nt >= R0 + 15 + RDEPTH);
      int progNow = gateSeen;
      if (gatev && gateSeen < nt - RDEPTH)
        progNow = __hip_atomic_load(&prog[linkUp * 16], __ATOMIC_RELAXED,
                                    __HIP_MEMORY_SCOPE_AGENT);

      accx(xA, (d + 2) & 1);
      stx(xB);  // x(d+3)
      ldg();    // px = x(d+4)

      if (qLive) {
        int spin = 0;
        while ((unsigned short)(qv >> 48) != (unsigned short)q &&
               spin < (1 << 22)) {
          ++spin;
          __builtin_amdgcn_s_sleep(1);
          qv = __hip_atomic_load(qs, __ATOMIC_RELAXED,
                                 __HIP_MEMORY_SCOPE_AGENT);
        }
        *(unsigned short*)(gbh + (q & 7) * 128 + L * 2) =
            (unsigned short)(qv >> 32);
        gbc[(q & 7) * 64 + L] = __uint_as_float((unsigned)qv);
      }
      if (meAct && L == 0)
        __hip_atomic_store(&prog[linkDn * 16], min(d + 1, R0 + 126),
                           __ATOMIC_RELAXED, __HIP_MEMORY_SCOPE_AGENT);
      if (gatev) {
        if (progNow > gateSeen) gateSeen = progNow;
        int spin = 0;
        while (gateSeen < nt - RDEPTH && spin < (1 << 22)) {
          ++spin;
          __builtin_amdgcn_s_sleep(1);
          gateSeen = __hip_atomic_load(&prog[linkUp * 16], __ATOMIC_RELAXED,
                                       __HIP_MEMORY_SCOPE_AGENT);
        }
      }
    }

    // rotate buffers (uniform, cheap pointer swaps)
    {
      unsigned char* t0 = xA; xA = xB; xB = xC; xC = t0;
      unsigned char* t1 = Pc; Pc = Pp; Pp = t1;
    }
    barrier_lds();  // single barrier: all LDS writes -> next step's reads
  }
}

extern "C" void kernel_launch(void* const* d_in, const int* in_sizes, int n_in,
                              void* d_out, int out_size, void* d_ws, size_t ws_size,
                              hipStream_t stream) {
  const float* x = (const float*)d_in[0];
  const float* Wk = (const float*)d_in[1];
  const float* Wr = (const float*)d_in[2];
  const float* b = (const float*)d_in[3];
  float* out = (float*)d_out;
  // reset ring tags + progress flags every launch (graph-replay determinism)
  hipMemsetAsync(d_ws, 0, PROG_OFF + NLINK * 16 * sizeof(int), stream);
  hipLaunchKernelGGL(mdrnn_kernel, dim3(128), dim3(512), 0, stream, x, Wk, Wr,
                     b, out, (char*)d_ws);
}

// Round 8
// 225.781 us; speedup vs baseline: 1.4110x; 1.0335x over previous
//
#include <hip/hip_runtime.h>

typedef __bf16 bf16x8 __attribute__((ext_vector_type(8)));
typedef __bf16 bf16x4 __attribute__((ext_vector_type(4)));
typedef float f32x4 __attribute__((ext_vector_type(4)));
typedef unsigned long long u64;

#define NCH 8            // row-chunks per recurrence
#define CELLS 16         // rows per chunk
#define NG 256           // 4 gates * 64 units
#define L2E 1.44269504089f
#define RDEPTH 16                       // ring depth (tag mod 16)
#define NLINK (16 * 7)                  // (g, producer ch 0..6)
#define RING_U64 (NLINK * RDEPTH * 64)  // 896 KiB
#define PROG_OFF (RING_U64 * 8)         // byte offset of progress flags

__device__ __forceinline__ unsigned short f2bfbits(float f) {
  __bf16 b = (__bf16)f;
  return __builtin_bit_cast(unsigned short, b);
}
__device__ __forceinline__ float bfbits2f(unsigned short s) {
  return (float)__builtin_bit_cast(__bf16, s);
}
// LDS-only barrier: vmcnt stays in flight (out stores, x prefetch, ring ops)
__device__ __forceinline__ void barrier_lds() {
  asm volatile("s_waitcnt lgkmcnt(0)" ::: "memory");
  __builtin_amdgcn_s_barrier();
}
// 16B-granule XOR swizzle for 128B bf16 rows (row 0 identity -> linear).
__device__ __forceinline__ int hix(int row, int byteoff) {
  return row * 128 + (byteoff ^ ((row & 7) << 4));
}

// ROW-partitioned 2D-LSTM pipeline; WAVE-SPECIALIZED single-barrier step.
// Timing model: total = tau * p; tau = 143 + 7*Lambda, Lambda = per-hop lag
// in periods = max(fill-pin, in-loop poll resolve ~16.8, geometric 16).
// A chunk cannot catch up (same period as upstream) so the INITIAL lag
// persists — R7's preloop blocked on tag R0+2 (upstream local 18), pinning
// Lambda~18.3 and masking the in-loop lookahead reduction. This round the
// preloop resolves ONLY tags R0-1,R0 (deadline: upstream local 16) and the
// in-loop poll takes over from q=R0+1 -> Lambda ~16.8, tau 271->~261.
// Block = (chunk ch, recurrence g), 512 thr = 8 waves (2/SIMD):
//   waves 0-3 (compute): {2x ds_read_b128 of pre-summed A-rows (P) + guard
//     reads, 16 h@Wr MFMA chained from C=accA(prefetched), znx prefetch,
//     LSTM epilogue (j=3 first -> DIRECT ring publish + early shuffles),
//     presum pass, out stores, zacc <- znx}. Publish is pack+store only —
//     the ring-wrap gate for tag d was validated by wave 6 at step d-1.
//   waves 4-7 (helper): accA(d+2)=x@Wk+b (8 MFMA) -> zbuf dbuf; stage
//     x(d+3)->xt tri-buf, prefetch x(d+4).
//     waves 4/5 alternate by parity: resolve ring tag d+1 (issue-early /
//       resolve-late), write gbh/gbc, update prog.
//     wave 6: pre-validates ring-wrap gate for tag d+1 (prog load issued
//       early, checked late; spins only if downstream lags > RDEPTH-1).
__global__ __launch_bounds__(512, 1) void mdrnn_kernel(
    const float* __restrict__ x, const float* __restrict__ Wk,
    const float* __restrict__ Wr, const float* __restrict__ bias,
    float* __restrict__ out, char* __restrict__ ws) {
  __shared__ __align__(16) unsigned char xt[3][CELLS * 128];    // 6 KiB
  __shared__ __align__(16) unsigned char Pbuf[2][CELLS * 128];  // 4 KiB
  __shared__ __align__(16) unsigned char gbh[8 * 128];          // 1 KiB
  __shared__ __align__(16) float gbc[8 * 64];                   // 2 KiB
  __shared__ __align__(16) float zbuf[2][4096];                 // 32 KiB

  u64* __restrict__ ring = (u64*)ws;
  int* __restrict__ prog = (int*)(ws + PROG_OFF);  // 16-int (64B) stride

  const int tid = threadIdx.x;
  const bool isComp = (tid < 256);
  const int L = tid & 63;
  const int lo16 = L & 15;
  const int hi16 = L >> 4;
  const int wq = (tid >> 6) & 3;     // wave id within compute/helper group
  const int u = wq * 16 + lo16;      // unit-group index (both roles)
  const int hm0 = (tid >> 4) & 15;   // helper: staged row
  const int hq16 = tid & 15;         // helper: channel quad

  const int ch = blockIdx.x >> 4;   // bx%8 == g%8 -> chain on one XCD
  const int g = blockIdx.x & 15;
  const int f = g >> 2;
  const int bb = g & 3;
  const int fh = (f >> 1) & 1;
  const int fw = f & 1;
  const int R0 = ch * CELLS;
  const int D1 = R0 + 142;
  const int linkDn = g * 7 + ch - 1;
  const int linkUp = g * 7 + ch;

  for (int i = tid; i < 3 * CELLS * 32; i += 512) ((int*)xt)[i] = 0;
  for (int i = tid; i < 2 * CELLS * 32; i += 512) ((int*)Pbuf)[i] = 0;
  for (int i = tid; i < 8 * 32; i += 512) ((int*)gbh)[i] = 0;
  for (int i = tid; i < 8 * 64; i += 512) gbc[i] = 0.f;

  // ---- per-role constants ----
  float bsc[4] = {0.f, 0.f, 0.f, 0.f};
  bf16x8 wkh[4][2], wrh[4][2], wrl[4][2];
  int oidx[4];
  int oStep = 0, cbase = 0;
  int o_ph0 = 0, o_ph1 = 0;
  int o_pw[4] = {0, 0, 0, 0};
  if (isComp) {
    const float* Wrf = Wr + f * (64 * NG);
#pragma unroll
    for (int t = 0; t < 4; ++t) {
      const float st = (t == 2) ? (2.f * L2E) : L2E;
#pragma unroll
      for (int kt = 0; kt < 2; ++kt)
#pragma unroll
        for (int jj = 0; jj < 8; ++jj) {
          int k = kt * 32 + hi16 * 8 + jj;
          float vr = Wrf[k * NG + t * 64 + u] * st;
          __bf16 vh = (__bf16)vr;
          wrh[t][kt][jj] = vh;
          wrl[t][kt][jj] = (__bf16)(vr - (float)vh);
        }
    }
    const int ccStep = fw ? -1 : 1;
#pragma unroll
    for (int j = 0; j < 4; ++j) {
      int ro = R0 + hi16 * 4 + j;
      int rr = fh ? 127 - ro : ro;
      int c0 = R0 - ro;
      oidx[j] = ((bb * 128 + rr) * 128 + (fw ? 127 - c0 : c0)) * NG + f * 64 + u;
      o_pw[j] = hix(hi16 * 4 + j, u * 2);
    }
    oStep = ccStep * NG;
    cbase = -hi16 * 4;
    o_ph0 = hix(lo16, hi16 * 16);       // presummed A-row lo16, k 0..31
    o_ph1 = hix(lo16, 64 + hi16 * 16);  // k 32..63
  } else {
    const float* Wkf = Wk + f * (64 * NG);
#pragma unroll
    for (int t = 0; t < 4; ++t) {
      const float st = (t == 2) ? (2.f * L2E) : L2E;
      bsc[t] = bias[f * NG + t * 64 + u] * st;
#pragma unroll
      for (int kt = 0; kt < 2; ++kt)
#pragma unroll
        for (int jj = 0; jj < 8; ++jj) {
          int k = kt * 32 + hi16 * 8 + jj;
          wkh[t][kt][jj] = (__bf16)(Wkf[k * NG + t * 64 + u] * st);
        }
    }
  }
  const int o_ax0 = hix(lo16, hi16 * 16);
  const int o_ax1 = hix(lo16, 64 + hi16 * 16);

  // ---- helper-wave x addressing ----
  const int ccStepH = fw ? -1 : 1;
  const int rx = R0 + hm0;
  const int rrx = fh ? 127 - rx : rx;
  int cx = R0 - rx;
  int xidx = ((bb * 128 + rrx) * 128 + (fw ? 127 - cx : cx)) * 64 + hq16 * 4;
  const int xStep = ccStepH * 64;
  float4 px;
  bool pxv = false;
  auto ldg = [&]() {
    pxv = ((unsigned)cx <= 127u);
    px = make_float4(0.f, 0.f, 0.f, 0.f);
    if (pxv) px = *(const float4*)(x + xidx);
    xidx += xStep;
    ++cx;
  };
  auto stx = [&](unsigned char* buf) {
    if (pxv) {
      bf16x4 pk;
      pk[0] = (__bf16)px.x; pk[1] = (__bf16)px.y;
      pk[2] = (__bf16)px.z; pk[3] = (__bf16)px.w;
      *(bf16x4*)(buf + hix(hm0, hq16 * 8)) = pk;
    }
  };
  // helper: accA(tile) = x@Wk + b -> zbuf[bi] (conflict-free b128 lanes)
  auto accx = [&](const unsigned char* xp, int bi) {
    bf16x8 a0 = *(const bf16x8*)(xp + o_ax0);
    bf16x8 a1 = *(const bf16x8*)(xp + o_ax1);
    float* zw = &zbuf[bi][0] + (wq * 64 + L) * 4;
#pragma unroll
    for (int t = 0; t < 4; ++t) {
      f32x4 az = (f32x4){bsc[t], bsc[t], bsc[t], bsc[t]};
      az = __builtin_amdgcn_mfma_f32_16x16x32_bf16(a0, wkh[t][0], az, 0, 0, 0);
      az = __builtin_amdgcn_mfma_f32_16x16x32_bf16(a1, wkh[t][1], az, 0, 0, 0);
      *(f32x4*)(zw + t * 1024) = az;
    }
  };

  __syncthreads();  // S0: zero-init visible

  if (!isComp) {
    ldg();                       // px = x(R0)
    stx(&xt[R0 % 3][0]);
    ldg();                       // px = x(R0+1)
  }
  __syncthreads();  // S1: xt(R0) visible

  if (!isComp) {
    stx(&xt[(R0 + 1) % 3][0]);   // stage x(R0+1)
    ldg();                       // px = x(R0+2)
    accx(&xt[R0 % 3][0], R0 & 1);
    // pre-loop poll (wave 4): ONLY tags R0-1, R0 (the two compute step R0
    // reads from gbh). Not blocking on R0+1/R0+2 unpins the fill lag: the
    // in-loop parity polls resolve them one step ahead of their consumers.
    if (wq == 0 && ch > 0) {
#pragma unroll
      for (int k = 0; k < 2; ++k) {
        const int q = R0 - 1 + k;
        u64* src = ring + ((linkDn * RDEPTH + (q & (RDEPTH - 1))) << 6) + L;
        u64 v;
        int spin = 0;
        for (;;) {
          v = __hip_atomic_load(src, __ATOMIC_RELAXED, __HIP_MEMORY_SCOPE_AGENT);
          if ((unsigned short)(v >> 48) == (unsigned short)q ||
              spin >= (1 << 22))
            break;
          ++spin;
          __builtin_amdgcn_s_sleep(1);
        }
        *(unsigned short*)(gbh + (q & 7) * 128 + L * 2) =
            (unsigned short)(v >> 32);
        gbc[(q & 7) * 64 + L] = __uint_as_float((unsigned)v);
        if (k == 0)  // P(R0-1)[row0] = guard h (scale 1; rest stays zero)
          *(unsigned short*)(&Pbuf[(R0 + 1) & 1][0] + L * 2) =
              (unsigned short)(v >> 32);
      }
      if (L == 0)
        __hip_atomic_store(&prog[linkDn * 16], R0, __ATOMIC_RELAXED,
                           __HIP_MEMORY_SCOPE_AGENT);
    }
  }
  __syncthreads();  // S2: xt(R0+1), zbuf(R0), gbh/gbc, P-init visible

  // ---- compute-wave carried state ----
  f32x4 zacc[4];
  float hnprev[4];  // this lane's h(d-1)[rows lm] (masked)
  float csj[4];     // presummed c for the CURRENT step
  float puv[4];     // carried c_ul = prev step's c_up
  int gateSeen = 0;  // helper wave 6 only
  if (isComp) {
    const float* zb = &zbuf[R0 & 1][0] + (wq * 64 + L) * 4;
#pragma unroll
    for (int t = 0; t < 4; ++t) zacc[t] = *(const f32x4*)(zb + t * 1024);
    const float cu0 = gbc[((R0 - 1) & 7) * 64 + u];  // zero for ch==0
#pragma unroll
    for (int j = 0; j < 4; ++j) {
      const float ci = (hi16 == 0 && j == 0) ? cu0 : 0.f;
      csj[j] = ci;
      puv[j] = ci;
      hnprev[j] = 0.f;
    }
    __builtin_amdgcn_s_setprio(1);  // compute waves favored over helpers
  } else {
    accx(&xt[(R0 + 1) % 3][0], (R0 + 1) & 1);
    stx(&xt[(R0 + 2) % 3][0]);   // stage x(R0+2)
    ldg();                       // px = x(R0+3)
  }
  __syncthreads();  // S3: zbuf(R0+1), xt(R0+2) visible

  // rotating pointers (uniform)
  unsigned char* Pc = &Pbuf[R0 & 1][0];        // written this step
  unsigned char* Pp = &Pbuf[(R0 + 1) & 1][0];  // read this step
  unsigned char* xA = &xt[(R0 + 2) % 3][0];    // accx read (x(d+2))
  unsigned char* xB = &xt[R0 % 3][0];          // stx write (x(d+3))
  unsigned char* xC = &xt[(R0 + 1) % 3][0];

  for (int d = R0; d <= D1; ++d) {
    if (isComp) {
      // ---- post-barrier critical region: 2 loads -> 16 MFMA ----
      bf16x8 pa0 = *(const bf16x8*)(Pp + o_ph0);
      bf16x8 pa1 = *(const bf16x8*)(Pp + o_ph1);
      // guard reads hoisted pre-MFMA (latency hides under MFMAs); row-0
      // swizzle of gbh rows is identity (linear). Stale slots only feed
      // masked-out rows.
      const float gh1 = bfbits2f(*(const unsigned short*)(gbh + (d & 7) * 128 + u * 2));
      const float gh2 = bfbits2f(*(const unsigned short*)(gbh + ((d - 1) & 7) * 128 + u * 2));
      const float gc1 = gbc[(d & 7) * 64 + u];
#pragma unroll
      for (int t = 0; t < 4; ++t)
        zacc[t] = __builtin_amdgcn_mfma_f32_16x16x32_bf16(pa0, wrh[t][0], zacc[t], 0, 0, 0);
#pragma unroll
      for (int t = 0; t < 4; ++t)
        zacc[t] = __builtin_amdgcn_mfma_f32_16x16x32_bf16(pa1, wrh[t][1], zacc[t], 0, 0, 0);
#pragma unroll
      for (int t = 0; t < 4; ++t)
        zacc[t] = __builtin_amdgcn_mfma_f32_16x16x32_bf16(pa0, wrl[t][0], zacc[t], 0, 0, 0);
#pragma unroll
      for (int t = 0; t < 4; ++t)
        zacc[t] = __builtin_amdgcn_mfma_f32_16x16x32_bf16(pa1, wrl[t][1], zacc[t], 0, 0, 0);

      // ---- prefetch accA(d+1) EARLY (zbuf[(d+1)&1] stable all step d);
      //      ds_read latency hides under the epilogue transcendentals ----
      const float* zbn = &zbuf[(d + 1) & 1][0] + (wq * 64 + L) * 4;
      const f32x4 znx0 = *(const f32x4*)(zbn);
      const f32x4 znx1 = *(const f32x4*)(zbn + 1024);
      const f32x4 znx2 = *(const f32x4*)(zbn + 2048);
      const f32x4 znx3 = *(const f32x4*)(zbn + 3072);

      const bool pubW = (ch < NCH - 1) && (d >= R0 + 15);

      // ---- epilogue: j=3 first (feeds publish + cross-row shuffles) ----
      float hcur[4], cnew[4];
      {
        const int cj = cbase - 3;
        const bool ok = ((unsigned)cj <= 127u);
        const float inv = (cj == 0) ? 1.f : (1.f / 3.f);  // lm>=3 -> r>0
        const float cpj = csj[3] * inv;
        const float e1 = __builtin_amdgcn_exp2f(-zacc[1][3]);  // zf
        const float e2 = __builtin_amdgcn_exp2f(-zacc[0][3]);  // zi
        const float e3 = __builtin_amdgcn_exp2f(zacc[2][3]);   // zg
        const float A = 1.f + e1, Bv = 1.f + e2, Cv = 1.f + e3;
        const float BC = Bv * Cv;
        float cn = (cpj * BC + (e3 - 1.f) * A) *
                   __builtin_amdgcn_rcpf(A * BC);
        const float e4 = __builtin_amdgcn_exp2f(-zacc[3][3]);  // zo
        const float e5 = __builtin_amdgcn_exp2f(2.f * L2E * cn);
        float hn = (e5 - 1.f) * __builtin_amdgcn_rcpf((1.f + e4) * (1.f + e5));
        if (pubW && hi16 == 3) {  // DIRECT publish: pack + store, no gate
          u64 v = ((u64)(unsigned short)d << 48) | ((u64)f2bfbits(hn) << 32) |
                  (u64)__float_as_uint(cn);
          u64* dst = ring + ((linkUp * RDEPTH + (d & (RDEPTH - 1))) << 6) + u;
          __hip_atomic_store(dst, v, __ATOMIC_RELAXED,
                             __HIP_MEMORY_SCOPE_AGENT);
        }
        hcur[3] = ok ? hn : 0.f;
        cnew[3] = ok ? cn : 0.f;
      }
      // issue cross-row shuffles early (hide ds_bpermute under j=2..0)
      const unsigned pk =
          ((unsigned)f2bfbits(hcur[3]) << 16) | f2bfbits(hnprev[3]);
      const unsigned pku = __shfl((int)pk, (L - 16) & 63);
      const float up_c = __shfl(cnew[3], (L - 16) & 63);
#pragma unroll
      for (int jj = 0; jj < 3; ++jj) {
        const int j = 2 - jj;
        const int cj = cbase - j;
        const bool ok = ((unsigned)cj <= 127u);
        const float inv =
            (cj == 0 || (j == 0 && R0 == 0 && hi16 == 0)) ? 1.f : (1.f / 3.f);
        const float cpj = csj[j] * inv;
        const float e1 = __builtin_amdgcn_exp2f(-zacc[1][j]);  // zf
        const float e2 = __builtin_amdgcn_exp2f(-zacc[0][j]);  // zi
        const float e3 = __builtin_amdgcn_exp2f(zacc[2][j]);   // zg
        const float A = 1.f + e1, Bv = 1.f + e2, Cv = 1.f + e3;
        const float BC = Bv * Cv;
        float cn = (cpj * BC + (e3 - 1.f) * A) *
                   __builtin_amdgcn_rcpf(A * BC);
        const float e4 = __builtin_amdgcn_exp2f(-zacc[3][j]);  // zo
        const float e5 = __builtin_amdgcn_exp2f(2.f * L2E * cn);
        float hn = (e5 - 1.f) * __builtin_amdgcn_rcpf((1.f + e4) * (1.f + e5));
        hcur[j] = ok ? hn : 0.f;
        cnew[j] = ok ? cn : 0.f;
      }
      const float up_h = bfbits2f((unsigned short)(pku >> 16));
      const float up_hp = bfbits2f((unsigned short)(pku & 0xffff));

      // ---- producer presum pass: P(d) rows + csj for step d+1 ----
#pragma unroll
      for (int j = 0; j < 4; ++j) {
        const float hup = j ? hcur[j - 1] : (hi16 ? up_h : gh1);
        const float hulp = j ? hnprev[j - 1] : (hi16 ? up_hp : gh2);
        const float sPj =
            ((cbase + 1 == j) || (R0 == 0 && hi16 == 0 && j == 0))
                ? 1.f : (1.f / 3.f);
        *(unsigned short*)(Pc + o_pw[j]) =
            f2bfbits(sPj * (hup + hcur[j] + hulp));
        const float cun = j ? cnew[j - 1] : (hi16 ? up_c : gc1);
        csj[j] = cun + cnew[j] + puv[j];
        puv[j] = cun;
      }
      // ---- out stores after P-write (pure sinks, off the lgkm path) ----
#pragma unroll
      for (int j = 0; j < 4; ++j) {
        if ((unsigned)(cbase - j) <= 127u) out[oidx[j]] = hcur[j];
        hnprev[j] = hcur[j];
        oidx[j] += oStep;
      }
      ++cbase;

      // ---- tail: commit prefetched accA(d+1) ----
      zacc[0] = znx0; zacc[1] = znx1; zacc[2] = znx2; zacc[3] = znx3;
    } else {
      // ---- helpers: poll/gate ISSUE -> accx -> stage -> RESOLVE ----
      const bool meAct = (ch > 0) && (wq == ((d - R0) & 1));
      const int q = d + 1;  // lookahead 1 == helper-mediated minimum
      const bool qLive = meAct && (q >= R0 + 1) && (q <= R0 + 126);
      const u64* qs = ring + ((linkDn * RDEPTH + (q & (RDEPTH - 1))) << 6) + L;
      u64 qv = 0;
      if (qLive)
        qv = __hip_atomic_load(qs, __ATOMIC_RELAXED, __HIP_MEMORY_SCOPE_AGENT);
      // wave 6: pre-validate ring-wrap gate for tag d+1 (compute publishes
      // it next step; barrier orders this pass before that publish).
      const int nt = d + 1;
      const bool gatev = (wq == 2) && (ch < NCH - 1) && (nt <= D1) &&
                         (nt >= R0 + 15 + RDEPTH);
      int progNow = gateSeen;
      if (gatev && gateSeen < nt - RDEPTH)
        progNow = __hip_atomic_load(&prog[linkUp * 16], __ATOMIC_RELAXED,
                                    __HIP_MEMORY_SCOPE_AGENT);

      accx(xA, (d + 2) & 1);
      stx(xB);  // x(d+3)
      ldg();    // px = x(d+4)

      if (qLive) {
        int spin = 0;
        while ((unsigned short)(qv >> 48) != (unsigned short)q &&
               spin < (1 << 22)) {
          ++spin;
          __builtin_amdgcn_s_sleep(1);
          qv = __hip_atomic_load(qs, __ATOMIC_RELAXED,
                                 __HIP_MEMORY_SCOPE_AGENT);
        }
        *(unsigned short*)(gbh + (q & 7) * 128 + L * 2) =
            (unsigned short)(qv >> 32);
        gbc[(q & 7) * 64 + L] = __uint_as_float((unsigned)qv);
      }
      if (meAct && L == 0)
        __hip_atomic_store(&prog[linkDn * 16], min(d + 1, R0 + 126),
                           __ATOMIC_RELAXED, __HIP_MEMORY_SCOPE_AGENT);
      if (gatev) {
        if (progNow > gateSeen) gateSeen = progNow;
        int spin = 0;
        while (gateSeen < nt - RDEPTH && spin < (1 << 22)) {
          ++spin;
          __builtin_amdgcn_s_sleep(1);
          gateSeen = __hip_atomic_load(&prog[linkUp * 16], __ATOMIC_RELAXED,
                                       __HIP_MEMORY_SCOPE_AGENT);
        }
      }
    }

    // rotate buffers (uniform, cheap pointer swaps)
    {
      unsigned char* t0 = xA; xA = xB; xB = xC; xC = t0;
      unsigned char* t1 = Pc; Pc = Pp; Pp = t1;
    }
    barrier_lds();  // single barrier: all LDS writes -> next step's reads
  }
}

extern "C" void kernel_launch(void* const* d_in, const int* in_sizes, int n_in,
                              void* d_out, int out_size, void* d_ws, size_t ws_size,
                              hipStream_t stream) {
  const float* x = (const float*)d_in[0];
  const float* Wk = (const float*)d_in[1];
  const float* Wr = (const float*)d_in[2];
  const float* b = (const float*)d_in[3];
  float* out = (float*)d_out;
  // reset ring tags + progress flags every launch (graph-replay determinism)
  hipMemsetAsync(d_ws, 0, PROG_OFF + NLINK * 16 * sizeof(int), stream);
  hipLaunchKernelGGL(mdrnn_kernel, dim3(128), dim3(512), 0, stream, x, Wk, Wr,
                     b, out, (char*)d_ws);
}

// Round 10
// 222.717 us; speedup vs baseline: 1.4304x; 1.0138x over previous
//
#include <hip/hip_runtime.h>

typedef __bf16 bf16x8 __attribute__((ext_vector_type(8)));
typedef __bf16 bf16x4 __attribute__((ext_vector_type(4)));
typedef float f32x4 __attribute__((ext_vector_type(4)));
typedef unsigned long long u64;

#define NCH 8            // row-chunks per recurrence
#define CELLS 16         // rows per chunk
#define NG 256           // 4 gates * 64 units
#define L2E 1.44269504089f
#define RDEPTH 16                       // ring depth (tag mod 16)
#define NLINK (16 * 7)                  // (g, producer ch 0..6)
#define RING_U64 (NLINK * RDEPTH * 64)  // 896 KiB
#define PROG_OFF (RING_U64 * 8)         // byte offset of progress flags

__device__ __forceinline__ unsigned short f2bfbits(float f) {
  __bf16 b = (__bf16)f;
  return __builtin_bit_cast(unsigned short, b);
}
__device__ __forceinline__ float bfbits2f(unsigned short s) {
  return (float)__builtin_bit_cast(__bf16, s);
}
// LDS-only barrier: vmcnt stays in flight (out stores, x loads, ring ops)
__device__ __forceinline__ void barrier_lds() {
  asm volatile("s_waitcnt lgkmcnt(0)" ::: "memory");
  __builtin_amdgcn_s_barrier();
}
// 16B-granule XOR swizzle for 128B bf16 rows (row 0 identity -> linear).
__device__ __forceinline__ int hix(int row, int byteoff) {
  return row * 128 + (byteoff ^ ((row & 7) << 4));
}

// ROW-partitioned 2D-LSTM pipeline; WAVE-SPECIALIZED single-barrier step.
// R8 base (verified protocol) minus the zbuf accA handoff: compute waves
// build accA(d+1) = b + x(d+1)@Wk THEMSELVES in the tail shadow (R1's
// placement, R2-A/B'd as ~free on the compute path) from the same xt bits
// and same wkh -> bit-identical zacc without the 32KB/step LDS roundtrip.
// Helpers lose accx entirely (step = poll + stx + ldg + gate -> shorter
// straggler) and load no weights. Protocol byte-identical to R8.
// Block = (chunk ch, recurrence g), 512 thr = 8 waves (2/SIMD):
//   waves 0-3 (compute): {2x ds_read_b128 of pre-summed A-rows (P) + x-frag
//     reads (xC = x(d+1)) + guard reads, 16 h@Wr MFMA chained from
//     C=accA, LSTM epilogue (j=3 first -> DIRECT ring publish + early
//     shuffles), presum pass, out stores, shadow accA(d+1) = b + x@Wk}.
//   waves 4-7 (helper): stage x(d+3)->xt tri-buf, prefetch x(d+4).
//     waves 4/5 alternate by parity: resolve ring tag d+1 (issue-early /
//       resolve-late), write gbh/gbc, update prog.
//     wave 6: pre-validates ring-wrap gate for tag d+1 (prog load issued
//       early, checked late; spins only if downstream lags > RDEPTH-1).
__global__ __launch_bounds__(512, 1) void mdrnn_kernel(
    const float* __restrict__ x, const float* __restrict__ Wk,
    const float* __restrict__ Wr, const float* __restrict__ bias,
    float* __restrict__ out, char* __restrict__ ws) {
  __shared__ __align__(16) unsigned char xt[3][CELLS * 128];    // 6 KiB
  __shared__ __align__(16) unsigned char Pbuf[2][CELLS * 128];  // 4 KiB
  __shared__ __align__(16) unsigned char gbh[8 * 128];          // 1 KiB
  __shared__ __align__(16) float gbc[8 * 64];                   // 2 KiB

  u64* __restrict__ ring = (u64*)ws;
  int* __restrict__ prog = (int*)(ws + PROG_OFF);  // 16-int (64B) stride

  const int tid = threadIdx.x;
  const bool isComp = (tid < 256);
  const int L = tid & 63;
  const int lo16 = L & 15;
  const int hi16 = L >> 4;
  const int wq = (tid >> 6) & 3;     // wave id within compute/helper group
  const int u = wq * 16 + lo16;      // unit-group index (both roles)
  const int hm0 = (tid >> 4) & 15;   // helper: staged row
  const int hq16 = tid & 15;         // helper: channel quad

  const int ch = blockIdx.x >> 4;   // bx%8 == g%8 -> chain on one XCD
  const int g = blockIdx.x & 15;
  const int f = g >> 2;
  const int bb = g & 3;
  const int fh = (f >> 1) & 1;
  const int fw = f & 1;
  const int R0 = ch * CELLS;
  const int D1 = R0 + 142;
  const int linkDn = g * 7 + ch - 1;
  const int linkUp = g * 7 + ch;

  for (int i = tid; i < 3 * CELLS * 32; i += 512) ((int*)xt)[i] = 0;
  for (int i = tid; i < 2 * CELLS * 32; i += 512) ((int*)Pbuf)[i] = 0;
  for (int i = tid; i < 8 * 32; i += 512) ((int*)gbh)[i] = 0;
  for (int i = tid; i < 8 * 64; i += 512) gbc[i] = 0.f;

  // ---- compute-wave constants (helpers need no weights now) ----
  float bsc[4] = {0.f, 0.f, 0.f, 0.f};
  bf16x8 wkh[4][2], wrh[4][2], wrl[4][2];
  int oidx[4];
  int oStep = 0, cbase = 0;
  int o_ph0 = 0, o_ph1 = 0;
  int o_pw[4] = {0, 0, 0, 0};
  if (isComp) {
    const float* Wrf = Wr + f * (64 * NG);
    const float* Wkf = Wk + f * (64 * NG);
#pragma unroll
    for (int t = 0; t < 4; ++t) {
      const float st = (t == 2) ? (2.f * L2E) : L2E;
      bsc[t] = bias[f * NG + t * 64 + u] * st;
#pragma unroll
      for (int kt = 0; kt < 2; ++kt)
#pragma unroll
        for (int jj = 0; jj < 8; ++jj) {
          int k = kt * 32 + hi16 * 8 + jj;
          float vr = Wrf[k * NG + t * 64 + u] * st;
          __bf16 vh = (__bf16)vr;
          wrh[t][kt][jj] = vh;
          wrl[t][kt][jj] = (__bf16)(vr - (float)vh);
          wkh[t][kt][jj] = (__bf16)(Wkf[k * NG + t * 64 + u] * st);
        }
    }
    const int ccStep = fw ? -1 : 1;
#pragma unroll
    for (int j = 0; j < 4; ++j) {
      int ro = R0 + hi16 * 4 + j;
      int rr = fh ? 127 - ro : ro;
      int c0 = R0 - ro;
      oidx[j] = ((bb * 128 + rr) * 128 + (fw ? 127 - c0 : c0)) * NG + f * 64 + u;
      o_pw[j] = hix(hi16 * 4 + j, u * 2);
    }
    oStep = ccStep * NG;
    cbase = -hi16 * 4;
    o_ph0 = hix(lo16, hi16 * 16);       // presummed A-row lo16, k 0..31
    o_ph1 = hix(lo16, 64 + hi16 * 16);  // k 32..63
  }
  const int o_ax0 = hix(lo16, hi16 * 16);
  const int o_ax1 = hix(lo16, 64 + hi16 * 16);

  // ---- helper-wave x addressing ----
  const int ccStepH = fw ? -1 : 1;
  const int rx = R0 + hm0;
  const int rrx = fh ? 127 - rx : rx;
  int cx = R0 - rx;
  int xidx = ((bb * 128 + rrx) * 128 + (fw ? 127 - cx : cx)) * 64 + hq16 * 4;
  const int xStep = ccStepH * 64;
  float4 px;
  bool pxv = false;
  auto ldg = [&]() {
    pxv = ((unsigned)cx <= 127u);
    px = make_float4(0.f, 0.f, 0.f, 0.f);
    if (pxv) px = *(const float4*)(x + xidx);
    xidx += xStep;
    ++cx;
  };
  auto stx = [&](unsigned char* buf) {
    if (pxv) {
      bf16x4 pk;
      pk[0] = (__bf16)px.x; pk[1] = (__bf16)px.y;
      pk[2] = (__bf16)px.z; pk[3] = (__bf16)px.w;
      *(bf16x4*)(buf + hix(hm0, hq16 * 8)) = pk;
    }
  };

  __syncthreads();  // S0: zero-init visible

  if (!isComp) {
    ldg();                       // px = x(R0)
    stx(&xt[R0 % 3][0]);
    ldg();                       // px = x(R0+1)
  }
  __syncthreads();  // S1: xt(R0) visible

  if (!isComp) {
    stx(&xt[(R0 + 1) % 3][0]);   // stage x(R0+1)
    ldg();                       // px = x(R0+2)
    // pre-loop poll (wave 4): ONLY tags R0-1, R0 (the two compute step R0
    // reads from gbh); in-loop parity polls take over from q=R0+1.
    if (wq == 0 && ch > 0) {
#pragma unroll
      for (int k = 0; k < 2; ++k) {
        const int q = R0 - 1 + k;
        u64* src = ring + ((linkDn * RDEPTH + (q & (RDEPTH - 1))) << 6) + L;
        u64 v;
        int spin = 0;
        for (;;) {
          v = __hip_atomic_load(src, __ATOMIC_RELAXED, __HIP_MEMORY_SCOPE_AGENT);
          if ((unsigned short)(v >> 48) == (unsigned short)q ||
              spin >= (1 << 22))
            break;
          ++spin;
          __builtin_amdgcn_s_sleep(1);
        }
        *(unsigned short*)(gbh + (q & 7) * 128 + L * 2) =
            (unsigned short)(v >> 32);
        gbc[(q & 7) * 64 + L] = __uint_as_float((unsigned)v);
        if (k == 0)  // P(R0-1)[row0] = guard h (scale 1; rest stays zero)
          *(unsigned short*)(&Pbuf[(R0 + 1) & 1][0] + L * 2) =
              (unsigned short)(v >> 32);
      }
      if (L == 0)
        __hip_atomic_store(&prog[linkDn * 16], R0, __ATOMIC_RELAXED,
                           __HIP_MEMORY_SCOPE_AGENT);
    }
  }
  __syncthreads();  // S2: xt(R0+1), gbh/gbc, P-init visible

  // ---- compute-wave carried state ----
  f32x4 zacc[4];
  float hnprev[4];  // this lane's h(d-1)[rows lm] (masked)
  float csj[4];     // presummed c for the CURRENT step
  float puv[4];     // carried c_ul = prev step's c_up
  int gateSeen = 0;  // helper wave 6 only
  if (isComp) {
    // prologue accA(R0) = b + x(R0)@Wk directly from xt (same bits zbuf
    // used to carry -> bit-identical)
    const unsigned char* xp = &xt[R0 % 3][0];
    bf16x8 a0 = *(const bf16x8*)(xp + o_ax0);
    bf16x8 a1 = *(const bf16x8*)(xp + o_ax1);
#pragma unroll
    for (int t = 0; t < 4; ++t) {
      zacc[t] = (f32x4){bsc[t], bsc[t], bsc[t], bsc[t]};
      zacc[t] = __builtin_amdgcn_mfma_f32_16x16x32_bf16(a0, wkh[t][0], zacc[t], 0, 0, 0);
      zacc[t] = __builtin_amdgcn_mfma_f32_16x16x32_bf16(a1, wkh[t][1], zacc[t], 0, 0, 0);
    }
    const float cu0 = gbc[((R0 - 1) & 7) * 64 + u];  // zero for ch==0
#pragma unroll
    for (int j = 0; j < 4; ++j) {
      const float ci = (hi16 == 0 && j == 0) ? cu0 : 0.f;
      csj[j] = ci;
      puv[j] = ci;
      hnprev[j] = 0.f;
    }
    __builtin_amdgcn_s_setprio(1);  // compute waves favored over helpers
  } else {
    stx(&xt[(R0 + 2) % 3][0]);   // stage x(R0+2)
    ldg();                       // px = x(R0+3)
  }
  __syncthreads();  // S3: xt(R0+2) visible

  // rotating pointers (uniform)
  unsigned char* Pc = &Pbuf[R0 & 1][0];        // written this step
  unsigned char* Pp = &Pbuf[(R0 + 1) & 1][0];  // read this step
  unsigned char* xA = &xt[(R0 + 2) % 3][0];    // in-flight (x(d+2))
  unsigned char* xB = &xt[R0 % 3][0];          // stx write (x(d+3))
  unsigned char* xC = &xt[(R0 + 1) % 3][0];    // compute shadow read x(d+1)

  for (int d = R0; d <= D1; ++d) {
    if (isComp) {
      // ---- post-barrier critical region: P read -> 16 MFMA ----
      bf16x8 pa0 = *(const bf16x8*)(Pp + o_ph0);
      bf16x8 pa1 = *(const bf16x8*)(Pp + o_ph1);
      // x-frags for the tail shadow (xC stable all step; latency hides
      // under MFMAs/epilogue)
      bf16x8 a0 = *(const bf16x8*)(xC + o_ax0);
      bf16x8 a1 = *(const bf16x8*)(xC + o_ax1);
      // guard reads hoisted pre-MFMA; row-0 swizzle of gbh is identity.
      const float gh1 = bfbits2f(*(const unsigned short*)(gbh + (d & 7) * 128 + u * 2));
      const float gh2 = bfbits2f(*(const unsigned short*)(gbh + ((d - 1) & 7) * 128 + u * 2));
      const float gc1 = gbc[(d & 7) * 64 + u];
#pragma unroll
      for (int t = 0; t < 4; ++t)
        zacc[t] = __builtin_amdgcn_mfma_f32_16x16x32_bf16(pa0, wrh[t][0], zacc[t], 0, 0, 0);
#pragma unroll
      for (int t = 0; t < 4; ++t)
        zacc[t] = __builtin_amdgcn_mfma_f32_16x16x32_bf16(pa1, wrh[t][1], zacc[t], 0, 0, 0);
#pragma unroll
      for (int t = 0; t < 4; ++t)
        zacc[t] = __builtin_amdgcn_mfma_f32_16x16x32_bf16(pa0, wrl[t][0], zacc[t], 0, 0, 0);
#pragma unroll
      for (int t = 0; t < 4; ++t)
        zacc[t] = __builtin_amdgcn_mfma_f32_16x16x32_bf16(pa1, wrl[t][1], zacc[t], 0, 0, 0);

      const bool pubW = (ch < NCH - 1) && (d >= R0 + 15);

      // ---- epilogue: j=3 first (feeds publish + cross-row shuffles) ----
      float hcur[4], cnew[4];
      {
        const int cj = cbase - 3;
        const bool ok = ((unsigned)cj <= 127u);
        const float inv = (cj == 0) ? 1.f : (1.f / 3.f);  // lm>=3 -> r>0
        const float cpj = csj[3] * inv;
        const float e1 = __builtin_amdgcn_exp2f(-zacc[1][3]);  // zf
        const float e2 = __builtin_amdgcn_exp2f(-zacc[0][3]);  // zi
        const float e3 = __builtin_amdgcn_exp2f(zacc[2][3]);   // zg
        const float A = 1.f + e1, Bv = 1.f + e2, Cv = 1.f + e3;
        const float BC = Bv * Cv;
        float cn = (cpj * BC + (e3 - 1.f) * A) *
                   __builtin_amdgcn_rcpf(A * BC);
        const float e4 = __builtin_amdgcn_exp2f(-zacc[3][3]);  // zo
        const float e5 = __builtin_amdgcn_exp2f(2.f * L2E * cn);
        float hn = (e5 - 1.f) * __builtin_amdgcn_rcpf((1.f + e4) * (1.f + e5));
        if (pubW && hi16 == 3) {  // DIRECT publish: pack + store, no gate
          u64 v = ((u64)(unsigned short)d << 48) | ((u64)f2bfbits(hn) << 32) |
                  (u64)__float_as_uint(cn);
          u64* dst = ring + ((linkUp * RDEPTH + (d & (RDEPTH - 1))) << 6) + u;
          __hip_atomic_store(dst, v, __ATOMIC_RELAXED,
                             __HIP_MEMORY_SCOPE_AGENT);
        }
        hcur[3] = ok ? hn : 0.f;
        cnew[3] = ok ? cn : 0.f;
      }
      // issue cross-row shuffles early (hide ds_bpermute under j=2..0)
      const unsigned pk =
          ((unsigned)f2bfbits(hcur[3]) << 16) | f2bfbits(hnprev[3]);
      const unsigned pku = __shfl((int)pk, (L - 16) & 63);
      const float up_c = __shfl(cnew[3], (L - 16) & 63);
#pragma unroll
      for (int jj = 0; jj < 3; ++jj) {
        const int j = 2 - jj;
        const int cj = cbase - j;
        const bool ok = ((unsigned)cj <= 127u);
        const float inv =
            (cj == 0 || (j == 0 && R0 == 0 && hi16 == 0)) ? 1.f : (1.f / 3.f);
        const float cpj = csj[j] * inv;
        const float e1 = __builtin_amdgcn_exp2f(-zacc[1][j]);  // zf
        const float e2 = __builtin_amdgcn_exp2f(-zacc[0][j]);  // zi
        const float e3 = __builtin_amdgcn_exp2f(zacc[2][j]);   // zg
        const float A = 1.f + e1, Bv = 1.f + e2, Cv = 1.f + e3;
        const float BC = Bv * Cv;
        float cn = (cpj * BC + (e3 - 1.f) * A) *
                   __builtin_amdgcn_rcpf(A * BC);
        const float e4 = __builtin_amdgcn_exp2f(-zacc[3][j]);  // zo
        const float e5 = __builtin_amdgcn_exp2f(2.f * L2E * cn);
        float hn = (e5 - 1.f) * __builtin_amdgcn_rcpf((1.f + e4) * (1.f + e5));
        hcur[j] = ok ? hn : 0.f;
        cnew[j] = ok ? cn : 0.f;
      }
      const float up_h = bfbits2f((unsigned short)(pku >> 16));
      const float up_hp = bfbits2f((unsigned short)(pku & 0xffff));

      // ---- producer presum pass: P(d) rows + csj for step d+1 ----
#pragma unroll
      for (int j = 0; j < 4; ++j) {
        const float hup = j ? hcur[j - 1] : (hi16 ? up_h : gh1);
        const float hulp = j ? hnprev[j - 1] : (hi16 ? up_hp : gh2);
        const float sPj =
            ((cbase + 1 == j) || (R0 == 0 && hi16 == 0 && j == 0))
                ? 1.f : (1.f / 3.f);
        *(unsigned short*)(Pc + o_pw[j]) =
            f2bfbits(sPj * (hup + hcur[j] + hulp));
        const float cun = j ? cnew[j - 1] : (hi16 ? up_c : gc1);
        csj[j] = cun + cnew[j] + puv[j];
        puv[j] = cun;
      }
      // ---- out stores after P-write (pure sinks, off the lgkm path) ----
#pragma unroll
      for (int j = 0; j < 4; ++j) {
        if ((unsigned)(cbase - j) <= 127u) out[oidx[j]] = hcur[j];
        hnprev[j] = hcur[j];
        oidx[j] += oStep;
      }
      ++cbase;

      // ---- tail shadow: accA(d+1) = b + x(d+1)@Wk (frags read at top) --
#pragma unroll
      for (int t = 0; t < 4; ++t) {
        zacc[t] = (f32x4){bsc[t], bsc[t], bsc[t], bsc[t]};
        zacc[t] = __builtin_amdgcn_mfma_f32_16x16x32_bf16(a0, wkh[t][0], zacc[t], 0, 0, 0);
        zacc[t] = __builtin_amdgcn_mfma_f32_16x16x32_bf16(a1, wkh[t][1], zacc[t], 0, 0, 0);
      }
    } else {
      // ---- helpers: poll/gate ISSUE -> stage -> RESOLVE ----
      const bool meAct = (ch > 0) && (wq == ((d - R0) & 1));
      const int q = d + 1;  // lookahead 1
      const bool qLive = meAct && (q >= R0 + 1) && (q <= R0 + 126);
      const u64* qs = ring + ((linkDn * RDEPTH + (q & (RDEPTH - 1))) << 6) + L;
      u64 qv = 0;
      if (qLive)
        qv = __hip_atomic_load(qs, __ATOMIC_RELAXED, __HIP_MEMORY_SCOPE_AGENT);
      // wave 6: pre-validate ring-wrap gate for tag d+1 (compute publishes
      // it next step; barrier orders this pass before that publish).
      const int nt = d + 1;
      const bool gatev = (wq == 2) && (ch < NCH - 1) && (nt <= D1) &&
                         (nt >= R0 + 15 + RDEPTH);
      int progNow = gateSeen;
      if (gatev && gateSeen < nt - RDEPTH)
        progNow = __hip_atomic_load(&prog[linkUp * 16], __ATOMIC_RELAXED,
                                    __HIP_MEMORY_SCOPE_AGENT);

      stx(xB);  // x(d+3)
      ldg();    // px = x(d+4)

      if (qLive) {
        int spin = 0;
        while ((unsigned short)(qv >> 48) != (unsigned short)q &&
               spin < (1 << 22)) {
          ++spin;
          __builtin_amdgcn_s_sleep(1);
          qv = __hip_atomic_load(qs, __ATOMIC_RELAXED,
                                 __HIP_MEMORY_SCOPE_AGENT);
        }
        *(unsigned short*)(gbh + (q & 7) * 128 + L * 2) =
            (unsigned short)(qv >> 32);
        gbc[(q & 7) * 64 + L] = __uint_as_float((unsigned)qv);
      }
      if (meAct && L == 0)
        __hip_atomic_store(&prog[linkDn * 16], min(d + 1, R0 + 126),
                           __ATOMIC_RELAXED, __HIP_MEMORY_SCOPE_AGENT);
      if (gatev) {
        if (progNow > gateSeen) gateSeen = progNow;
        int spin = 0;
        while (gateSeen < nt - RDEPTH && spin < (1 << 22)) {
          ++spin;
          __builtin_amdgcn_s_sleep(1);
          gateSeen = __hip_atomic_load(&prog[linkUp * 16], __ATOMIC_RELAXED,
                                       __HIP_MEMORY_SCOPE_AGENT);
        }
      }
    }

    // rotate buffers (uniform, cheap pointer swaps)
    {
      unsigned char* t0 = xA; xA = xB; xB = xC; xC = t0;
      unsigned char* t1 = Pc; Pc = Pp; Pp = t1;
    }
    barrier_lds();  // single barrier: all LDS writes -> next step's reads
  }
}

extern "C" void kernel_launch(void* const* d_in, const int* in_sizes, int n_in,
                              void* d_out, int out_size, void* d_ws, size_t ws_size,
                              hipStream_t stream) {
  const float* x = (const float*)d_in[0];
  const float* Wk = (const float*)d_in[1];
  const float* Wr = (const float*)d_in[2];
  const float* b = (const float*)d_in[3];
  float* out = (float*)d_out;
  // reset ring tags + progress flags every launch (graph-replay determinism)
  hipMemsetAsync(d_ws, 0, PROG_OFF + NLINK * 16 * sizeof(int), stream);
  hipLaunchKernelGGL(mdrnn_kernel, dim3(128), dim3(512), 0, stream, x, Wk, Wr,
                     b, out, (char*)d_ws);
}